// Round 1
// baseline (304.282 us; speedup 1.0000x reference)
//
#include <hip/hip_runtime.h>
#include <hip/hip_bf16.h>
#include <stdint.h>

#define S_LEN  2048
#define HIDDEN 2048
#define NH     32
#define NKVH   8
#define HD     64
#define NHD    (NH*HD)    // 2048
#define KVD    (NKVH*HD)  // 512

typedef __attribute__((ext_vector_type(8))) short  short8;
typedef __attribute__((ext_vector_type(4))) short  short4v;
typedef __attribute__((ext_vector_type(4))) float  f32x4;
typedef __attribute__((ext_vector_type(4))) float  float4v;
typedef __attribute__((ext_vector_type(8))) __bf16 bf16x8;

__device__ __forceinline__ short f2bf(float x){
  uint32_t u = __builtin_bit_cast(uint32_t, x);
  u += 0x7fffu + ((u >> 16) & 1u);   // RNE; inputs are finite
  return (short)(u >> 16);
}

__device__ __forceinline__ f32x4 mfma_bf16(short8 a, short8 b, f32x4 c){
  return __builtin_amdgcn_mfma_f32_16x16x32_bf16(
      __builtin_bit_cast(bf16x8, a), __builtin_bit_cast(bf16x8, b), c, 0, 0, 0);
}

// ---------------- elementwise fp32 -> bf16 ----------------
__global__ __launch_bounds__(256) void k_f32_to_bf16(const float* __restrict__ X,
                                                     short* __restrict__ Y, int n4){
  int i = blockIdx.x*256 + threadIdx.x;
  if (i >= n4) return;
  float4v v = ((const float4v* __restrict__)X)[i];
  short4v o;
#pragma unroll
  for (int j=0;j<4;j++) o[j] = f2bf(v[j]);
  ((short4v* __restrict__)Y)[i] = o;
}

// ---------------- transpose fp32 (R x C) -> bf16 (C x R) ----------------
__global__ __launch_bounds__(256) void k_transpose(const float* __restrict__ W,
                                                   short* __restrict__ WT, int R, int C){
  __shared__ float tile[32][33];
  int x = threadIdx.x & 31, y0 = threadIdx.x >> 5;
  int c0 = blockIdx.x*32, r0 = blockIdx.y*32;
#pragma unroll
  for (int yy=y0; yy<32; yy+=8) tile[yy][x] = W[(size_t)(r0+yy)*C + c0 + x];
  __syncthreads();
#pragma unroll
  for (int yy=y0; yy<32; yy+=8) WT[(size_t)(c0+yy)*R + r0 + x] = f2bf(tile[x][yy]);
}

// ---------------- RoPE (+optional score-scale fold) fp32 -> bf16 ----------------
__global__ __launch_bounds__(256) void k_rope(const float* __restrict__ X,
                                              const float* __restrict__ cosT,
                                              const float* __restrict__ sinT,
                                              short* __restrict__ Y,
                                              int hshift, float scale){
  int idx = blockIdx.x*256 + threadIdx.x;     // one (s,h,d<32) pair per thread
  int d = idx & 31;
  int t = idx >> 5;                           // s*nheads + h
  int s = t >> hshift;
  int base = t*64;
  float x1 = X[base + d], x2 = X[base + d + 32];
  float c1 = cosT[s*64 + d],      s1 = sinT[s*64 + d];
  float c2 = cosT[s*64 + d + 32], s2 = sinT[s*64 + d + 32];
  Y[base + d]      = f2bf((x1*c1 - x2*s1)*scale);
  Y[base + d + 32] = f2bf((x2*c2 + x1*s2)*scale);
}

// ---------------- GEMM body: C[M,N] = A[M,K=2048] * BT[N,K]^T  (bf16 in, fp32 out)
__device__ __forceinline__ void gemm_body(const short* __restrict__ A,
                                          const short* __restrict__ BT,
                                          float* __restrict__ C,
                                          int Nc, int bm, int bn,
                                          short* As, short* Bs){
  const int K = HIDDEN;
  const int tid = threadIdx.x, wid = tid>>6, lane = tid&63;
  const int r = lane&15, g = lane>>4;
  const int wr = wid>>1, wc = wid&1;
  const int arow = tid>>2, ak = (tid&3)*8;

  const short* aA = A  + (size_t)(bm*128 + arow)*K + ak;
  const short* aB = BT + (size_t)(bn*128 + arow)*K + ak;

  f32x4 acc[4][4];
#pragma unroll
  for (int m=0;m<4;m++)
#pragma unroll
    for (int n=0;n<4;n++) acc[m][n] = (f32x4){0.f,0.f,0.f,0.f};

  // prefetch tile 0
  short8 ra0 = *(const short8*)(aA);
  short8 ra1 = *(const short8*)(aA + 64*K);
  short8 rb0 = *(const short8*)(aB);
  short8 rb1 = *(const short8*)(aB + 64*K);

  const int nkt = K/32;
  for (int kt=0; kt<nkt; ++kt){
    __syncthreads();                       // previous tile's reads done
    *(short8*)&As[arow*32 + ak]      = ra0;
    *(short8*)&As[(arow+64)*32 + ak] = ra1;
    *(short8*)&Bs[arow*32 + ak]      = rb0;
    *(short8*)&Bs[(arow+64)*32 + ak] = rb1;
    __syncthreads();                       // writes visible
    if (kt+1 < nkt){                       // issue next-tile loads before compute
      ra0 = *(const short8*)(aA + (kt+1)*32);
      ra1 = *(const short8*)(aA + (kt+1)*32 + 64*K);
      rb0 = *(const short8*)(aB + (kt+1)*32);
      rb1 = *(const short8*)(aB + (kt+1)*32 + 64*K);
    }
    short8 af[4], bf[4];
#pragma unroll
    for (int m=0;m<4;m++) af[m] = *(short8*)&As[(wr*64 + m*16 + r)*32 + g*8];
#pragma unroll
    for (int n=0;n<4;n++) bf[n] = *(short8*)&Bs[(wc*64 + n*16 + r)*32 + g*8];
#pragma unroll
    for (int m=0;m<4;m++)
#pragma unroll
      for (int n=0;n<4;n++) acc[m][n] = mfma_bf16(af[m], bf[n], acc[m][n]);
  }

#pragma unroll
  for (int m=0;m<4;m++)
#pragma unroll
    for (int n=0;n<4;n++)
#pragma unroll
      for (int j=0;j<4;j++)
        C[(size_t)(bm*128 + wr*64 + m*16 + g*4 + j)*Nc + bn*128 + wc*64 + n*16 + r]
          = acc[m][n][j];
}

__global__ __launch_bounds__(256) void k_gemm_qkv(const short* __restrict__ hsb,
                                                  const short* __restrict__ WqT,
                                                  const short* __restrict__ WkT,
                                                  const short* __restrict__ WvT,
                                                  float* __restrict__ Qf,
                                                  float* __restrict__ Kf,
                                                  float* __restrict__ Vf){
  __shared__ short As[128*32], Bs[128*32];
  int bn = blockIdx.x, bm = blockIdx.y;
  const short* BT; float* Cc; int Nc, bnl;
  if (bn < 16)      { BT = WqT; Cc = Qf; Nc = NHD; bnl = bn; }
  else if (bn < 20) { BT = WkT; Cc = Kf; Nc = KVD; bnl = bn-16; }
  else              { BT = WvT; Cc = Vf; Nc = KVD; bnl = bn-20; }
  gemm_body(hsb, BT, Cc, Nc, bm, bnl, As, Bs);
}

__global__ __launch_bounds__(256) void k_gemm(const short* __restrict__ A,
                                              const short* __restrict__ BT,
                                              float* __restrict__ C, int Nc){
  __shared__ short As[128*32], Bs[128*32];
  gemm_body(A, BT, C, Nc, blockIdx.y, blockIdx.x, As, Bs);
}

// ---------------- flash attention with block-causal+column bias ----------------
__global__ __launch_bounds__(256) void k_attn(const short* __restrict__ Qb,
                                              const short* __restrict__ Kb,
                                              const short* __restrict__ Vb,
                                              const int* __restrict__ nm,
                                              short* __restrict__ Ob){
  const int qt = gridDim.x - 1 - blockIdx.x;   // heavy q-tiles first
  const int h  = blockIdx.y;
  const int hk = h >> 2;                        // GQA group of 4
  const int bs = nm[0] + 1;
  const int tid = threadIdx.x, wid = tid>>6, lane = tid&63;
  const int r = lane&15, g = lane>>4;

  __shared__ short K_lds[64*72];      // [key][d], padded stride 72
  __shared__ short V_lds[64*72];      // [d][key] (transposed), padded
  __shared__ short P_lds[4][16*72];   // per-wave P, padded

  // Q fragments in registers (A-operand: row = lane&15)
  const int qrowA = qt*64 + wid*16 + r;
  short8 qf0 = *(const short8*)(Qb + (size_t)qrowA*NHD + h*HD + g*8);
  short8 qf1 = *(const short8*)(Qb + (size_t)qrowA*NHD + h*HD + 32 + g*8);

  // per-lane output rows (C-layout: row = g*4+j)
  int qglob[4], qdiv[4];
#pragma unroll
  for (int j=0;j<4;j++){ qglob[j] = qt*64 + wid*16 + g*4 + j; qdiv[j] = qglob[j]/bs; }

  // incremental div/mod state for key columns (cols n*16+r within tile)
  int kcol[4], kd[4], km[4];
#pragma unroll
  for (int n=0;n<4;n++){ kcol[n] = n*16 + r; kd[n] = kcol[n]/bs; km[n] = kcol[n]%bs; }
  const int d64 = 64/bs, r64 = 64%bs;

  float mrow[4], lrow[4];
  f32x4 acc[4];
#pragma unroll
  for (int j=0;j<4;j++){ mrow[j] = -1e30f; lrow[j] = 0.f; }
#pragma unroll
  for (int f=0;f<4;f++) acc[f] = (f32x4){0.f,0.f,0.f,0.f};

  const int trow = tid>>3, tc8 = (tid&7)*8;
  const short* Kg = Kb + hk*HD;
  const short* Vg = Vb + hk*HD;

  // prefetch kv tile 0
  short8 kr0 = *(const short8*)(Kg + (size_t)trow*KVD + tc8);
  short8 kr1 = *(const short8*)(Kg + (size_t)(trow+32)*KVD + tc8);
  short8 vr0 = *(const short8*)(Vg + (size_t)trow*KVD + tc8);
  short8 vr1 = *(const short8*)(Vg + (size_t)(trow+32)*KVD + tc8);

  for (int kt=0; kt<=qt; ++kt){
    __syncthreads();
    *(short8*)&K_lds[trow*72 + tc8]      = kr0;
    *(short8*)&K_lds[(trow+32)*72 + tc8] = kr1;
#pragma unroll
    for (int jj=0;jj<8;jj++){
      V_lds[(tc8+jj)*72 + trow]      = vr0[jj];
      V_lds[(tc8+jj)*72 + trow + 32] = vr1[jj];
    }
    __syncthreads();

    if (kt < qt){   // issue next tile's loads; latency hides under compute
      const short* Kn = Kg + (size_t)(kt+1)*64*KVD;
      const short* Vn = Vg + (size_t)(kt+1)*64*KVD;
      kr0 = *(const short8*)(Kn + (size_t)trow*KVD + tc8);
      kr1 = *(const short8*)(Kn + (size_t)(trow+32)*KVD + tc8);
      vr0 = *(const short8*)(Vn + (size_t)trow*KVD + tc8);
      vr1 = *(const short8*)(Vn + (size_t)(trow+32)*KVD + tc8);
    }

    // S = Q K^T (scale pre-folded into Q)
    f32x4 sc[4];
#pragma unroll
    for (int n=0;n<4;n++){
      short8 kf0 = *(short8*)&K_lds[(n*16+r)*72 + g*8];
      short8 kf1 = *(short8*)&K_lds[(n*16+r)*72 + 32 + g*8];
      f32x4 z = (f32x4){0.f,0.f,0.f,0.f};
      z = mfma_bf16(qf0, kf0, z);
      sc[n] = mfma_bf16(qf1, kf1, z);
    }

    // bias mask: allowed = (k<=q) && (k%bs==0 || k/bs==q/bs)
#pragma unroll
    for (int n=0;n<4;n++){
#pragma unroll
      for (int j=0;j<4;j++){
        bool ok = (kcol[n] <= qglob[j]) && ((km[n]==0) || (kd[n]==qdiv[j]));
        sc[n][j] = ok ? sc[n][j] : -1e30f;
      }
    }

    // online softmax (row stats across 16 lanes of same g-group)
    float fac[4];
#pragma unroll
    for (int j=0;j<4;j++){
      float v = fmaxf(fmaxf(sc[0][j], sc[1][j]), fmaxf(sc[2][j], sc[3][j]));
      v = fmaxf(v, __shfl_xor(v, 1));
      v = fmaxf(v, __shfl_xor(v, 2));
      v = fmaxf(v, __shfl_xor(v, 4));
      v = fmaxf(v, __shfl_xor(v, 8));
      float mn = fmaxf(mrow[j], v);
      fac[j] = __expf(mrow[j] - mn);
      mrow[j] = mn;
    }
    float rs[4] = {0.f,0.f,0.f,0.f};
#pragma unroll
    for (int n=0;n<4;n++)
#pragma unroll
      for (int j=0;j<4;j++){
        float p = __expf(sc[n][j] - mrow[j]);
        rs[j] += p;
        sc[n][j] = p;
      }
#pragma unroll
    for (int j=0;j<4;j++){
      float v = rs[j];
      v += __shfl_xor(v, 1);
      v += __shfl_xor(v, 2);
      v += __shfl_xor(v, 4);
      v += __shfl_xor(v, 8);
      lrow[j] = lrow[j]*fac[j] + v;
    }
#pragma unroll
    for (int f=0;f<4;f++)
#pragma unroll
      for (int j=0;j<4;j++) acc[f][j] *= fac[j];

    // P -> LDS (bf16), then O += P @ V
#pragma unroll
    for (int n=0;n<4;n++)
#pragma unroll
      for (int j=0;j<4;j++)
        P_lds[wid][(g*4+j)*72 + n*16 + r] = f2bf(sc[n][j]);

    short8 pf0 = *(short8*)&P_lds[wid][r*72 + g*8];
    short8 pf1 = *(short8*)&P_lds[wid][r*72 + 32 + g*8];
#pragma unroll
    for (int f=0;f<4;f++){
      short8 vf0 = *(short8*)&V_lds[(f*16+r)*72 + g*8];
      short8 vf1 = *(short8*)&V_lds[(f*16+r)*72 + 32 + g*8];
      acc[f] = mfma_bf16(pf0, vf0, acc[f]);
      acc[f] = mfma_bf16(pf1, vf1, acc[f]);
    }

    // advance key-column div/mod by +64
#pragma unroll
    for (int n=0;n<4;n++){
      kcol[n] += 64;
      km[n] += r64; kd[n] += d64;
      if (km[n] >= bs){ km[n] -= bs; kd[n] += 1; }
    }
  }

  // epilogue: O /= l, write bf16
#pragma unroll
  for (int j=0;j<4;j++){
    float inv = 1.f / lrow[j];
#pragma unroll
    for (int f=0;f<4;f++)
      Ob[(size_t)qglob[j]*NHD + h*HD + f*16 + r] = f2bf(acc[f][j]*inv);
  }
}

// ---------------- launch ----------------
extern "C" void kernel_launch(void* const* d_in, const int* in_sizes, int n_in,
                              void* d_out, int out_size, void* d_ws, size_t ws_size,
                              hipStream_t stream){
  const float* hs   = (const float*)d_in[0];
  const float* cosT = (const float*)d_in[1];
  const float* sinT = (const float*)d_in[2];
  const float* Wq   = (const float*)d_in[3];
  const float* Wk   = (const float*)d_in[4];
  const float* Wv   = (const float*)d_in[5];
  const float* Wo   = (const float*)d_in[6];
  const int*   nm   = (const int*)d_in[7];

  char* ws = (char*)d_ws;
  short* hsb  = (short*)(ws);                   // 8 MB
  short* WqT  = (short*)(ws + (8ull<<20));      // 8 MB
  short* WkT  = (short*)(ws + (16ull<<20));     // 2 MB
  short* WvT  = (short*)(ws + (18ull<<20));     // 2 MB
  short* WoT  = (short*)(ws + (20ull<<20));     // 8 MB
  float* Qf   = (float*)(ws + (28ull<<20));     // 16 MB
  float* Kf   = (float*)(ws + (44ull<<20));     // 4 MB
  float* Vf   = (float*)(ws + (48ull<<20));     // 4 MB
  short* Qb   = (short*)(ws + (52ull<<20));     // 8 MB
  short* Kb   = (short*)(ws + (60ull<<20));     // 2 MB
  short* Vb   = (short*)(ws + (62ull<<20));     // 2 MB
  short* attnb= (short*)(ws + (64ull<<20));     // 8 MB
  float* out  = (float*)d_out;

  k_f32_to_bf16<<<(S_LEN*HIDDEN/4+255)/256, 256, 0, stream>>>(hs, hsb, S_LEN*HIDDEN/4);
  k_transpose<<<dim3(NHD/32, HIDDEN/32), 256, 0, stream>>>(Wq, WqT, HIDDEN, NHD);
  k_transpose<<<dim3(KVD/32, HIDDEN/32), 256, 0, stream>>>(Wk, WkT, HIDDEN, KVD);
  k_transpose<<<dim3(KVD/32, HIDDEN/32), 256, 0, stream>>>(Wv, WvT, HIDDEN, KVD);
  k_transpose<<<dim3(HIDDEN/32, NHD/32), 256, 0, stream>>>(Wo, WoT, NHD, HIDDEN);

  k_gemm_qkv<<<dim3(24, 16), 256, 0, stream>>>(hsb, WqT, WkT, WvT, Qf, Kf, Vf);

  k_rope<<<(S_LEN*NH*32)/256, 256, 0, stream>>>(Qf, cosT, sinT, Qb, 5, 0.125f);
  k_rope<<<(S_LEN*NKVH*32)/256, 256, 0, stream>>>(Kf, cosT, sinT, Kb, 3, 1.0f);
  k_f32_to_bf16<<<(S_LEN*KVD/4+255)/256, 256, 0, stream>>>(Vf, Vb, S_LEN*KVD/4);

  k_attn<<<dim3(S_LEN/64, NH), 256, 0, stream>>>(Qb, Kb, Vb, nm, attnb);

  k_gemm<<<dim3(NHD/128, S_LEN/128), 256, 0, stream>>>(attnb, WoT, out, HIDDEN);
}

// Round 2
// 180.351 us; speedup vs baseline: 1.6872x; 1.6872x over previous
//
#include <hip/hip_runtime.h>
#include <hip/hip_bf16.h>
#include <stdint.h>

#define S_LEN  2048
#define HIDDEN 2048
#define NH     32
#define NKVH   8
#define HD     64
#define NHD    (NH*HD)    // 2048
#define KVD    (NKVH*HD)  // 512

typedef __attribute__((ext_vector_type(8))) short  short8;
typedef __attribute__((ext_vector_type(4))) short  short4v;
typedef __attribute__((ext_vector_type(4))) float  f32x4;
typedef __attribute__((ext_vector_type(4))) float  float4v;
typedef __attribute__((ext_vector_type(8))) __bf16 bf16x8;

__device__ __forceinline__ short f2bf(float x){
  uint32_t u = __builtin_bit_cast(uint32_t, x);
  u += 0x7fffu + ((u >> 16) & 1u);   // RNE; inputs are finite
  return (short)(u >> 16);
}

__device__ __forceinline__ f32x4 mfma_bf16(short8 a, short8 b, f32x4 c){
  return __builtin_amdgcn_mfma_f32_16x16x32_bf16(
      __builtin_bit_cast(bf16x8, a), __builtin_bit_cast(bf16x8, b), c, 0, 0, 0);
}

// ---------------- elementwise fp32 -> bf16 ----------------
__global__ __launch_bounds__(256) void k_f32_to_bf16(const float* __restrict__ X,
                                                     short* __restrict__ Y, int n4){
  int i = blockIdx.x*256 + threadIdx.x;
  if (i >= n4) return;
  float4v v = ((const float4v* __restrict__)X)[i];
  short4v o;
#pragma unroll
  for (int j=0;j<4;j++) o[j] = f2bf(v[j]);
  ((short4v* __restrict__)Y)[i] = o;
}

// ---------------- transpose fp32 (R x C) -> bf16 (C x R) ----------------
__global__ __launch_bounds__(256) void k_transpose(const float* __restrict__ W,
                                                   short* __restrict__ WT, int R, int C){
  __shared__ float tile[32][33];
  int x = threadIdx.x & 31, y0 = threadIdx.x >> 5;
  int c0 = blockIdx.x*32, r0 = blockIdx.y*32;
#pragma unroll
  for (int yy=y0; yy<32; yy+=8) tile[yy][x] = W[(size_t)(r0+yy)*C + c0 + x];
  __syncthreads();
#pragma unroll
  for (int yy=y0; yy<32; yy+=8) WT[(size_t)(c0+yy)*R + r0 + x] = f2bf(tile[x][yy]);
}

// ---------------- sparse-column V transpose: VTs[d][c] = V[bs*c][d] (bf16) -----
// row stride fixed S_LEN so host needn't know bs. Requires bs | 64.
__global__ __launch_bounds__(256) void k_vt_sparse(const float* __restrict__ Vf,
                                                   short* __restrict__ VTs,
                                                   const int* __restrict__ nm){
  int bs = nm[0] + 1;
  int Sc = S_LEN / bs;
  __shared__ float tile[32][33];
  int x = threadIdx.x & 31, y0 = threadIdx.x >> 5;
  int c0 = blockIdx.x*32, d0 = blockIdx.y*32;
  if (c0 >= Sc) return;
#pragma unroll
  for (int yy=y0; yy<32; yy+=8) tile[yy][x] = Vf[(size_t)(bs*(c0+yy))*KVD + d0 + x];
  __syncthreads();
#pragma unroll
  for (int yy=y0; yy<32; yy+=8) VTs[(size_t)(d0+yy)*S_LEN + c0 + x] = f2bf(tile[x][yy]);
}

// ---------------- RoPE (+optional score-scale fold) fp32 -> bf16 ----------------
__global__ __launch_bounds__(256) void k_rope(const float* __restrict__ X,
                                              const float* __restrict__ cosT,
                                              const float* __restrict__ sinT,
                                              short* __restrict__ Y,
                                              int hshift, float scale){
  int idx = blockIdx.x*256 + threadIdx.x;     // one (s,h,d<32) pair per thread
  int d = idx & 31;
  int t = idx >> 5;                           // s*nheads + h
  int s = t >> hshift;
  int base = t*64;
  float x1 = X[base + d], x2 = X[base + d + 32];
  float c1 = cosT[s*64 + d],      s1 = sinT[s*64 + d];
  float c2 = cosT[s*64 + d + 32], s2 = sinT[s*64 + d + 32];
  Y[base + d]      = f2bf((x1*c1 - x2*s1)*scale);
  Y[base + d + 32] = f2bf((x2*c2 + x1*s2)*scale);
}

// ---------------- GEMM body: C[M,N] = A[M,K=2048] * BT[N,K]^T  (bf16 in, fp32 out)
__device__ __forceinline__ void gemm_body(const short* __restrict__ A,
                                          const short* __restrict__ BT,
                                          float* __restrict__ C,
                                          int Nc, int bm, int bn,
                                          short* As, short* Bs){
  const int K = HIDDEN;
  const int tid = threadIdx.x, wid = tid>>6, lane = tid&63;
  const int r = lane&15, g = lane>>4;
  const int wr = wid>>1, wc = wid&1;
  const int arow = tid>>2, ak = (tid&3)*8;

  const short* aA = A  + (size_t)(bm*128 + arow)*K + ak;
  const short* aB = BT + (size_t)(bn*128 + arow)*K + ak;

  f32x4 acc[4][4];
#pragma unroll
  for (int m=0;m<4;m++)
#pragma unroll
    for (int n=0;n<4;n++) acc[m][n] = (f32x4){0.f,0.f,0.f,0.f};

  // prefetch tile 0
  short8 ra0 = *(const short8*)(aA);
  short8 ra1 = *(const short8*)(aA + 64*K);
  short8 rb0 = *(const short8*)(aB);
  short8 rb1 = *(const short8*)(aB + 64*K);

  const int nkt = K/32;
  for (int kt=0; kt<nkt; ++kt){
    __syncthreads();                       // previous tile's reads done
    *(short8*)&As[arow*32 + ak]      = ra0;
    *(short8*)&As[(arow+64)*32 + ak] = ra1;
    *(short8*)&Bs[arow*32 + ak]      = rb0;
    *(short8*)&Bs[(arow+64)*32 + ak] = rb1;
    __syncthreads();                       // writes visible
    if (kt+1 < nkt){                       // issue next-tile loads before compute
      ra0 = *(const short8*)(aA + (kt+1)*32);
      ra1 = *(const short8*)(aA + (kt+1)*32 + 64*K);
      rb0 = *(const short8*)(aB + (kt+1)*32);
      rb1 = *(const short8*)(aB + (kt+1)*32 + 64*K);
    }
    short8 af[4], bf[4];
#pragma unroll
    for (int m=0;m<4;m++) af[m] = *(short8*)&As[(wr*64 + m*16 + r)*32 + g*8];
#pragma unroll
    for (int n=0;n<4;n++) bf[n] = *(short8*)&Bs[(wc*64 + n*16 + r)*32 + g*8];
#pragma unroll
    for (int m=0;m<4;m++)
#pragma unroll
      for (int n=0;n<4;n++) acc[m][n] = mfma_bf16(af[m], bf[n], acc[m][n]);
  }

#pragma unroll
  for (int m=0;m<4;m++)
#pragma unroll
    for (int n=0;n<4;n++)
#pragma unroll
      for (int j=0;j<4;j++)
        C[(size_t)(bm*128 + wr*64 + m*16 + g*4 + j)*Nc + bn*128 + wc*64 + n*16 + r]
          = acc[m][n][j];
}

__global__ __launch_bounds__(256) void k_gemm_qkv(const short* __restrict__ hsb,
                                                  const short* __restrict__ WqT,
                                                  const short* __restrict__ WkT,
                                                  const short* __restrict__ WvT,
                                                  float* __restrict__ Qf,
                                                  float* __restrict__ Kf,
                                                  float* __restrict__ Vf){
  __shared__ short As[128*32], Bs[128*32];
  int bn = blockIdx.x, bm = blockIdx.y;
  const short* BT; float* Cc; int Nc, bnl;
  if (bn < 16)      { BT = WqT; Cc = Qf; Nc = NHD; bnl = bn; }
  else if (bn < 20) { BT = WkT; Cc = Kf; Nc = KVD; bnl = bn-16; }
  else              { BT = WvT; Cc = Vf; Nc = KVD; bnl = bn-20; }
  gemm_body(hsb, BT, Cc, Nc, bm, bnl, As, Bs);
}

__global__ __launch_bounds__(256) void k_gemm(const short* __restrict__ A,
                                              const short* __restrict__ BT,
                                              float* __restrict__ C, int Nc){
  __shared__ short As[128*32], Bs[128*32];
  gemm_body(A, BT, C, Nc, blockIdx.y, blockIdx.x, As, Bs);
}

// ---------------- attention: shared softmax/PV tail for one 64-key tile --------
__device__ __forceinline__ void sm_pv(f32x4 sc[2][4],
                                      float mrow[2][4], float lrow[2][4],
                                      f32x4 acc[2][4], short* Pw,
                                      const short* Vtile,   // [d][col], stride S_LEN
                                      int r, int g){
  // online softmax (rows = m*16+g*4+j; reduce across the 16 r-lanes)
#pragma unroll
  for (int m=0;m<2;m++){
#pragma unroll
    for (int j=0;j<4;j++){
      float v = fmaxf(fmaxf(sc[m][0][j], sc[m][1][j]), fmaxf(sc[m][2][j], sc[m][3][j]));
      v = fmaxf(v, __shfl_xor(v, 1));
      v = fmaxf(v, __shfl_xor(v, 2));
      v = fmaxf(v, __shfl_xor(v, 4));
      v = fmaxf(v, __shfl_xor(v, 8));
      float mn = fmaxf(mrow[m][j], v);
      float fac = __expf(mrow[m][j] - mn);
      mrow[m][j] = mn;
#pragma unroll
      for (int f=0;f<4;f++) acc[m][f][j] *= fac;
      float rs = 0.f;
#pragma unroll
      for (int n=0;n<4;n++){
        float p = __expf(sc[m][n][j] - mn);
        rs += p;
        sc[m][n][j] = p;
      }
      rs += __shfl_xor(rs, 1);
      rs += __shfl_xor(rs, 2);
      rs += __shfl_xor(rs, 4);
      rs += __shfl_xor(rs, 8);
      lrow[m][j] = lrow[m][j]*fac + rs;
    }
  }
  // P -> per-wave LDS (bf16), C-layout write, A-layout read (same wave: lgkm only)
#pragma unroll
  for (int m=0;m<2;m++)
#pragma unroll
    for (int n=0;n<4;n++)
#pragma unroll
      for (int j=0;j<4;j++)
        Pw[(m*16 + g*4 + j)*72 + n*16 + r] = f2bf(sc[m][n][j]);

  short8 pf[2][2];
#pragma unroll
  for (int m=0;m<2;m++)
#pragma unroll
    for (int kk=0;kk<2;kk++)
      pf[m][kk] = *(short8*)&Pw[(m*16 + r)*72 + kk*32 + g*8];

#pragma unroll
  for (int f=0;f<4;f++){
#pragma unroll
    for (int kk=0;kk<2;kk++){
      short8 vf = *(const short8*)(Vtile + (size_t)(f*16 + r)*S_LEN + kk*32 + g*8);
#pragma unroll
      for (int m=0;m<2;m++)
        acc[m][f] = mfma_bf16(pf[m][kk], vf, acc[m][f]);
    }
  }
}

// 128 q-rows/block, 4 independent waves (32 rows each), no barriers in loop.
// Column pass: dense over k=bs*c (no mask); diag pass: 2 tiles, full mask.
__global__ __launch_bounds__(256) void k_attn2(const short* __restrict__ Qb,
                                               const short* __restrict__ Kb,   // [S][KVD]
                                               const short* __restrict__ VT,   // [KVD][S]
                                               const short* __restrict__ VTs,  // [KVD][S/bs], stride S
                                               const int* __restrict__ nm,
                                               short* __restrict__ Ob){
  const int qb = gridDim.x - 1 - blockIdx.x;   // heavy q-blocks first
  const int h  = blockIdx.y;
  const int hk = h >> 2;
  const int bs = nm[0] + 1;                    // requires bs | 64 (holds for nm=3)

  const int tid = threadIdx.x, wid = tid>>6, lane = tid&63;
  const int r = lane&15, g = lane>>4;

  __shared__ short P_lds[4][32*72];
  short* Pw = &P_lds[wid][0];

  const int qlo = qb*128;
  const int rowbase = qlo + wid*32;

  // Q fragments (score scale pre-folded into Qb)
  short8 qf[2][2];
#pragma unroll
  for (int m=0;m<2;m++)
#pragma unroll
    for (int kk=0;kk<2;kk++)
      qf[m][kk] = *(const short8*)(Qb + (size_t)(rowbase + m*16 + r)*NHD + h*HD + kk*32 + g*8);

  f32x4 acc[2][4];
  float mrow[2][4], lrow[2][4];
#pragma unroll
  for (int m=0;m<2;m++){
#pragma unroll
    for (int f=0;f<4;f++) acc[m][f] = (f32x4){0.f,0.f,0.f,0.f};
#pragma unroll
    for (int j=0;j<4;j++){ mrow[m][j] = -1e30f; lrow[m][j] = 0.f; }
  }

  // hoisted div/mod by runtime bs (bs|64, bs|128 -> exact splits)
  const int b64 = 64/bs;
  int cd[4], cm[4];
#pragma unroll
  for (int n=0;n<4;n++){ int c = n*16 + r; cd[n] = c/bs; cm[n] = c%bs; }
  int qv[2][4], qd[2][4];
  const int qdbase = qlo/bs;
#pragma unroll
  for (int m=0;m<2;m++)
#pragma unroll
    for (int j=0;j<4;j++){
      int qrel = wid*32 + m*16 + g*4 + j;
      qv[m][j] = qlo + qrel;
      qd[m][j] = qdbase + qrel/bs;
    }

  const short* Kg  = Kb  + hk*HD;
  const short* Vsg = VTs + (size_t)hk*HD*S_LEN;
  const short* Vdg = VT  + (size_t)hk*HD*S_LEN;

  // ---- column pass: keys k = bs*c, c < cmax, all allowed ----
  const int cmax = qlo / bs;
  const int nct = (cmax + 63) >> 6;
  for (int ct=0; ct<nct; ++ct){
    const int cbase = ct*64;
    f32x4 sc[2][4];
#pragma unroll
    for (int n=0;n<4;n++){
      const int key = bs*(cbase + n*16 + r);
      short8 kf0 = *(const short8*)(Kg + (size_t)key*KVD + g*8);
      short8 kf1 = *(const short8*)(Kg + (size_t)key*KVD + 32 + g*8);
#pragma unroll
      for (int m=0;m<2;m++){
        f32x4 z = (f32x4){0.f,0.f,0.f,0.f};
        z = mfma_bf16(qf[m][0], kf0, z);
        sc[m][n] = mfma_bf16(qf[m][1], kf1, z);
      }
    }
    if (cmax - cbase < 64){                 // partial last tile only
#pragma unroll
      for (int n=0;n<4;n++){
        if (cbase + n*16 + r >= cmax){
#pragma unroll
          for (int m=0;m<2;m++)
#pragma unroll
            for (int j=0;j<4;j++) sc[m][n][j] = -1e30f;
        }
      }
    }
    sm_pv(sc, mrow, lrow, acc, Pw, Vsg + cbase, r, g);
  }

  // ---- diag pass: the 2 raw 64-key tiles covering this q-block ----
#pragma unroll
  for (int t=0;t<2;t++){
    const int kt = 2*qb + t;
    const int kbase = kt*64;
    const int kdb = kt*b64;
    f32x4 sc[2][4];
#pragma unroll
    for (int n=0;n<4;n++){
      const int key = kbase + n*16 + r;
      short8 kf0 = *(const short8*)(Kg + (size_t)key*KVD + g*8);
      short8 kf1 = *(const short8*)(Kg + (size_t)key*KVD + 32 + g*8);
#pragma unroll
      for (int m=0;m<2;m++){
        f32x4 z = (f32x4){0.f,0.f,0.f,0.f};
        z = mfma_bf16(qf[m][0], kf0, z);
        sc[m][n] = mfma_bf16(qf[m][1], kf1, z);
      }
    }
#pragma unroll
    for (int n=0;n<4;n++){
      const int key = kbase + n*16 + r;
      const int kd  = kdb + cd[n];
      const bool col = (cm[n] == 0);
#pragma unroll
      for (int m=0;m<2;m++)
#pragma unroll
        for (int j=0;j<4;j++){
          bool ok = (key <= qv[m][j]) && (col || (kd == qd[m][j]));
          sc[m][n][j] = ok ? sc[m][n][j] : -1e30f;
        }
    }
    sm_pv(sc, mrow, lrow, acc, Pw, Vdg + kbase, r, g);
  }

  // epilogue: O /= l, write bf16
#pragma unroll
  for (int m=0;m<2;m++)
#pragma unroll
    for (int j=0;j<4;j++){
      float inv = 1.f / lrow[m][j];
      int q = qv[m][j];
#pragma unroll
      for (int f=0;f<4;f++)
        Ob[(size_t)q*NHD + h*HD + f*16 + r] = f2bf(acc[m][f][j]*inv);
    }
}

// ---------------- launch ----------------
extern "C" void kernel_launch(void* const* d_in, const int* in_sizes, int n_in,
                              void* d_out, int out_size, void* d_ws, size_t ws_size,
                              hipStream_t stream){
  const float* hs   = (const float*)d_in[0];
  const float* cosT = (const float*)d_in[1];
  const float* sinT = (const float*)d_in[2];
  const float* Wq   = (const float*)d_in[3];
  const float* Wk   = (const float*)d_in[4];
  const float* Wv   = (const float*)d_in[5];
  const float* Wo   = (const float*)d_in[6];
  const int*   nm   = (const int*)d_in[7];

  char* ws = (char*)d_ws;
  short* hsb  = (short*)(ws);                   // 8 MB
  short* WqT  = (short*)(ws + (8ull<<20));      // 8 MB
  short* WkT  = (short*)(ws + (16ull<<20));     // 2 MB
  short* WvT  = (short*)(ws + (18ull<<20));     // 2 MB
  short* WoT  = (short*)(ws + (20ull<<20));     // 8 MB
  float* Qf   = (float*)(ws + (28ull<<20));     // 16 MB
  float* Kf   = (float*)(ws + (44ull<<20));     // 4 MB (reused as VTs after rope-K)
  short* VTs  = (short*)(ws + (44ull<<20));     // 2 MB (aliases Kf; written after rope-K)
  float* Vf   = (float*)(ws + (48ull<<20));     // 4 MB
  short* Qb   = (short*)(ws + (52ull<<20));     // 8 MB
  short* Kb   = (short*)(ws + (60ull<<20));     // 2 MB
  short* VT   = (short*)(ws + (62ull<<20));     // 2 MB
  short* attnb= (short*)(ws + (64ull<<20));     // 8 MB
  float* out  = (float*)d_out;

  k_f32_to_bf16<<<(S_LEN*HIDDEN/4+255)/256, 256, 0, stream>>>(hs, hsb, S_LEN*HIDDEN/4);
  k_transpose<<<dim3(NHD/32, HIDDEN/32), 256, 0, stream>>>(Wq, WqT, HIDDEN, NHD);
  k_transpose<<<dim3(KVD/32, HIDDEN/32), 256, 0, stream>>>(Wk, WkT, HIDDEN, KVD);
  k_transpose<<<dim3(KVD/32, HIDDEN/32), 256, 0, stream>>>(Wv, WvT, HIDDEN, KVD);
  k_transpose<<<dim3(HIDDEN/32, NHD/32), 256, 0, stream>>>(Wo, WoT, NHD, HIDDEN);

  k_gemm_qkv<<<dim3(24, 16), 256, 0, stream>>>(hsb, WqT, WkT, WvT, Qf, Kf, Vf);

  k_rope<<<(S_LEN*NH*32)/256, 256, 0, stream>>>(Qf, cosT, sinT, Qb, 5, 0.125f);
  k_rope<<<(S_LEN*NKVH*32)/256, 256, 0, stream>>>(Kf, cosT, sinT, Kb, 3, 1.0f);

  k_transpose<<<dim3(KVD/32, S_LEN/32), 256, 0, stream>>>(Vf, VT, S_LEN, KVD);
  k_vt_sparse<<<dim3(S_LEN/32, KVD/32), 256, 0, stream>>>(Vf, VTs, nm);

  k_attn2<<<dim3(S_LEN/128, NH), 256, 0, stream>>>(Qb, Kb, VT, VTs, nm, attnb);

  k_gemm<<<dim3(NHD/128, S_LEN/128), 256, 0, stream>>>(attnb, WoT, out, HIDDEN);
}

// Round 3
// 177.426 us; speedup vs baseline: 1.7150x; 1.0165x over previous
//
#include <hip/hip_runtime.h>
#include <hip/hip_bf16.h>
#include <stdint.h>

#define S_LEN  2048
#define HIDDEN 2048
#define NH     32
#define NKVH   8
#define HD     64
#define NHD    (NH*HD)    // 2048
#define KVD    (NKVH*HD)  // 512

typedef __attribute__((ext_vector_type(8))) short  short8;
typedef __attribute__((ext_vector_type(4))) short  short4v;
typedef __attribute__((ext_vector_type(4))) float  f32x4;
typedef __attribute__((ext_vector_type(4))) float  float4v;
typedef __attribute__((ext_vector_type(8))) __bf16 bf16x8;

__device__ __forceinline__ short f2bf(float x){
  uint32_t u = __builtin_bit_cast(uint32_t, x);
  u += 0x7fffu + ((u >> 16) & 1u);   // RNE; inputs are finite
  return (short)(u >> 16);
}

__device__ __forceinline__ f32x4 mfma_bf16(short8 a, short8 b, f32x4 c){
  return __builtin_amdgcn_mfma_f32_16x16x32_bf16(
      __builtin_bit_cast(bf16x8, a), __builtin_bit_cast(bf16x8, b), c, 0, 0, 0);
}

// async global->LDS, 16B per lane; LDS dest = wave-uniform base + lane*16
__device__ __forceinline__ void gload16(const short* g, short* l){
  __builtin_amdgcn_global_load_lds(
      (const __attribute__((address_space(1))) void*)g,
      (__attribute__((address_space(3))) void*)l, 16, 0, 0);
}

// ---------------- elementwise fp32 -> bf16 ----------------
__global__ __launch_bounds__(256) void k_f32_to_bf16(const float* __restrict__ X,
                                                     short* __restrict__ Y, int n4){
  int i = blockIdx.x*256 + threadIdx.x;
  if (i >= n4) return;
  float4v v = ((const float4v* __restrict__)X)[i];
  short4v o;
#pragma unroll
  for (int j=0;j<4;j++) o[j] = f2bf(v[j]);
  ((short4v* __restrict__)Y)[i] = o;
}

// ---------------- transpose fp32 (R x C) -> bf16 (C x R) ----------------
__global__ __launch_bounds__(256) void k_transpose(const float* __restrict__ W,
                                                   short* __restrict__ WT, int R, int C){
  __shared__ float tile[32][33];
  int x = threadIdx.x & 31, y0 = threadIdx.x >> 5;
  int c0 = blockIdx.x*32, r0 = blockIdx.y*32;
#pragma unroll
  for (int yy=y0; yy<32; yy+=8) tile[yy][x] = W[(size_t)(r0+yy)*C + c0 + x];
  __syncthreads();
#pragma unroll
  for (int yy=y0; yy<32; yy+=8) WT[(size_t)(c0+yy)*R + r0 + x] = f2bf(tile[x][yy]);
}

// ---------------- sparse-column V transpose: VTs[d][c] = V[bs*c][d] (bf16) -----
__global__ __launch_bounds__(256) void k_vt_sparse(const float* __restrict__ Vf,
                                                   short* __restrict__ VTs,
                                                   const int* __restrict__ nm){
  int bs = nm[0] + 1;
  int Sc = S_LEN / bs;
  __shared__ float tile[32][33];
  int x = threadIdx.x & 31, y0 = threadIdx.x >> 5;
  int c0 = blockIdx.x*32, d0 = blockIdx.y*32;
  if (c0 >= Sc) return;
#pragma unroll
  for (int yy=y0; yy<32; yy+=8) tile[yy][x] = Vf[(size_t)(bs*(c0+yy))*KVD + d0 + x];
  __syncthreads();
#pragma unroll
  for (int yy=y0; yy<32; yy+=8) VTs[(size_t)(d0+yy)*S_LEN + c0 + x] = f2bf(tile[x][yy]);
}

// ---------------- RoPE (+optional score-scale fold) fp32 -> bf16 ----------------
__global__ __launch_bounds__(256) void k_rope(const float* __restrict__ X,
                                              const float* __restrict__ cosT,
                                              const float* __restrict__ sinT,
                                              short* __restrict__ Y,
                                              int hshift, float scale){
  int idx = blockIdx.x*256 + threadIdx.x;     // one (s,h,d<32) pair per thread
  int d = idx & 31;
  int t = idx >> 5;                           // s*nheads + h
  int s = t >> hshift;
  int base = t*64;
  float x1 = X[base + d], x2 = X[base + d + 32];
  float c1 = cosT[s*64 + d],      s1 = sinT[s*64 + d];
  float c2 = cosT[s*64 + d + 32], s2 = sinT[s*64 + d + 32];
  Y[base + d]      = f2bf((x1*c1 - x2*s1)*scale);
  Y[base + d + 32] = f2bf((x2*c2 + x1*s2)*scale);
}

// ---- GEMM body: C[M,N] = A[M,K=2048] * BT[N,K]^T, 128x64 tile, gload_lds stage
__device__ __forceinline__ void gemm_body(const short* __restrict__ A,
                                          const short* __restrict__ BT,
                                          float* __restrict__ C,
                                          int Nc, int bm, int bn,
                                          short* As, short* Bs){
  const int K = HIDDEN;
  const int tid = threadIdx.x, wid = tid>>6, lane = tid&63;
  const int r = lane&15, g = lane>>4;
  const int wr = wid>>1, wc = wid&1;

  // staging: per-lane global src, linear LDS dest (wave base + lane*16B)
  const int srow = tid>>2, scol = (tid&3)*8;
  const short* gA0 = A  + (size_t)(bm*128 + srow)*K + scol;
  const short* gA1 = gA0 + (size_t)64*K;
  const short* gB0 = BT + (size_t)(bn*64 + srow)*K + scol;
  short* lA0 = As + wid*512;            // bytes: wid*1024
  short* lA1 = As + 2048 + wid*512;     // rows 64..127
  short* lB0 = Bs + wid*512;

  f32x4 acc[4][2];
#pragma unroll
  for (int m=0;m<4;m++)
#pragma unroll
    for (int n=0;n<2;n++) acc[m][n] = (f32x4){0.f,0.f,0.f,0.f};

  const int nkt = K/32;
  for (int kt=0; kt<nkt; ++kt){
    __syncthreads();                    // all waves done reading previous tile
    gload16(gA0 + kt*32, lA0);
    gload16(gA1 + kt*32, lA1);
    gload16(gB0 + kt*32, lB0);
    __syncthreads();                    // vmcnt(0) drained -> LDS visible

    short8 af[4], bf[2];
#pragma unroll
    for (int m=0;m<4;m++) af[m] = *(short8*)&As[(wr*64 + m*16 + r)*32 + g*8];
#pragma unroll
    for (int n=0;n<2;n++) bf[n] = *(short8*)&Bs[(wc*32 + n*16 + r)*32 + g*8];
#pragma unroll
    for (int m=0;m<4;m++)
#pragma unroll
      for (int n=0;n<2;n++) acc[m][n] = mfma_bf16(af[m], bf[n], acc[m][n]);
  }

#pragma unroll
  for (int m=0;m<4;m++)
#pragma unroll
    for (int n=0;n<2;n++)
#pragma unroll
      for (int j=0;j<4;j++)
        C[(size_t)(bm*128 + wr*64 + m*16 + g*4 + j)*Nc + bn*64 + wc*32 + n*16 + r]
          = acc[m][n][j];
}

__global__ __launch_bounds__(256) void k_gemm_qkv(const short* __restrict__ hsb,
                                                  const short* __restrict__ WqT,
                                                  const short* __restrict__ WkT,
                                                  const short* __restrict__ WvT,
                                                  float* __restrict__ Qf,
                                                  float* __restrict__ Kf,
                                                  float* __restrict__ Vf){
  __shared__ short As[128*32], Bs[64*32];
  int bn = blockIdx.x, bm = blockIdx.y;
  const short* BT; float* Cc; int Nc, bnl;
  if (bn < 32)      { BT = WqT; Cc = Qf; Nc = NHD; bnl = bn; }
  else if (bn < 40) { BT = WkT; Cc = Kf; Nc = KVD; bnl = bn-32; }
  else              { BT = WvT; Cc = Vf; Nc = KVD; bnl = bn-40; }
  gemm_body(hsb, BT, Cc, Nc, bm, bnl, As, Bs);
}

__global__ __launch_bounds__(256) void k_gemm(const short* __restrict__ A,
                                              const short* __restrict__ BT,
                                              float* __restrict__ C, int Nc){
  __shared__ short As[128*32], Bs[64*32];
  gemm_body(A, BT, C, Nc, blockIdx.y, blockIdx.x, As, Bs);
}

// ---------------- attention: shared softmax/PV tail for one 64-key tile --------
__device__ __forceinline__ void sm_pv(f32x4 sc[2][4],
                                      float mrow[2][4], float lrow[2][4],
                                      f32x4 acc[2][4], short* Pw,
                                      const short* Vtile,   // [d][col], stride S_LEN
                                      int r, int g){
#pragma unroll
  for (int m=0;m<2;m++){
#pragma unroll
    for (int j=0;j<4;j++){
      float v = fmaxf(fmaxf(sc[m][0][j], sc[m][1][j]), fmaxf(sc[m][2][j], sc[m][3][j]));
      v = fmaxf(v, __shfl_xor(v, 1));
      v = fmaxf(v, __shfl_xor(v, 2));
      v = fmaxf(v, __shfl_xor(v, 4));
      v = fmaxf(v, __shfl_xor(v, 8));
      float mn = fmaxf(mrow[m][j], v);
      float fac = __expf(mrow[m][j] - mn);
      mrow[m][j] = mn;
#pragma unroll
      for (int f=0;f<4;f++) acc[m][f][j] *= fac;
      float rs = 0.f;
#pragma unroll
      for (int n=0;n<4;n++){
        float p = __expf(sc[m][n][j] - mn);
        rs += p;
        sc[m][n][j] = p;
      }
      rs += __shfl_xor(rs, 1);
      rs += __shfl_xor(rs, 2);
      rs += __shfl_xor(rs, 4);
      rs += __shfl_xor(rs, 8);
      lrow[m][j] = lrow[m][j]*fac + rs;
    }
  }
  // P -> per-wave LDS (bf16), C-layout write, A-layout read (same wave: lgkm only)
#pragma unroll
  for (int m=0;m<2;m++)
#pragma unroll
    for (int n=0;n<4;n++)
#pragma unroll
      for (int j=0;j<4;j++)
        Pw[(m*16 + g*4 + j)*72 + n*16 + r] = f2bf(sc[m][n][j]);

  short8 pf[2][2];
#pragma unroll
  for (int m=0;m<2;m++)
#pragma unroll
    for (int kk=0;kk<2;kk++)
      pf[m][kk] = *(short8*)&Pw[(m*16 + r)*72 + kk*32 + g*8];

#pragma unroll
  for (int f=0;f<4;f++){
#pragma unroll
    for (int kk=0;kk<2;kk++){
      short8 vf = *(const short8*)(Vtile + (size_t)(f*16 + r)*S_LEN + kk*32 + g*8);
#pragma unroll
      for (int m=0;m<2;m++)
        acc[m][f] = mfma_bf16(pf[m][kk], vf, acc[m][f]);
    }
  }
}

// 128 q-rows/block, 4 independent waves (32 rows each), no barriers in loop.
__global__ __launch_bounds__(256) void k_attn2(const short* __restrict__ Qb,
                                               const short* __restrict__ Kb,   // [S][KVD]
                                               const short* __restrict__ VT,   // [KVD][S]
                                               const short* __restrict__ VTs,  // [KVD][S/bs], stride S
                                               const int* __restrict__ nm,
                                               short* __restrict__ Ob){
  const int qb = gridDim.x - 1 - blockIdx.x;   // heavy q-blocks first
  const int h  = blockIdx.y;
  const int hk = h >> 2;
  const int bs = nm[0] + 1;                    // requires bs | 64

  const int tid = threadIdx.x, wid = tid>>6, lane = tid&63;
  const int r = lane&15, g = lane>>4;

  __shared__ short P_lds[4][32*72];
  short* Pw = &P_lds[wid][0];

  const int qlo = qb*128;
  const int rowbase = qlo + wid*32;

  short8 qf[2][2];
#pragma unroll
  for (int m=0;m<2;m++)
#pragma unroll
    for (int kk=0;kk<2;kk++)
      qf[m][kk] = *(const short8*)(Qb + (size_t)(rowbase + m*16 + r)*NHD + h*HD + kk*32 + g*8);

  f32x4 acc[2][4];
  float mrow[2][4], lrow[2][4];
#pragma unroll
  for (int m=0;m<2;m++){
#pragma unroll
    for (int f=0;f<4;f++) acc[m][f] = (f32x4){0.f,0.f,0.f,0.f};
#pragma unroll
    for (int j=0;j<4;j++){ mrow[m][j] = -1e30f; lrow[m][j] = 0.f; }
  }

  const int b64 = 64/bs;
  int cd[4], cm[4];
#pragma unroll
  for (int n=0;n<4;n++){ int c = n*16 + r; cd[n] = c/bs; cm[n] = c%bs; }
  int qv[2][4], qd[2][4];
  const int qdbase = qlo/bs;
#pragma unroll
  for (int m=0;m<2;m++)
#pragma unroll
    for (int j=0;j<4;j++){
      int qrel = wid*32 + m*16 + g*4 + j;
      qv[m][j] = qlo + qrel;
      qd[m][j] = qdbase + qrel/bs;
    }

  const short* Kg  = Kb  + hk*HD;
  const short* Vsg = VTs + (size_t)hk*HD*S_LEN;
  const short* Vdg = VT  + (size_t)hk*HD*S_LEN;

  // ---- column pass: keys k = bs*c, c < cmax, all allowed ----
  const int cmax = qlo / bs;
  const int nct = (cmax + 63) >> 6;
  for (int ct=0; ct<nct; ++ct){
    const int cbase = ct*64;
    f32x4 sc[2][4];
#pragma unroll
    for (int n=0;n<4;n++){
      const int key = bs*(cbase + n*16 + r);
      short8 kf0 = *(const short8*)(Kg + (size_t)key*KVD + g*8);
      short8 kf1 = *(const short8*)(Kg + (size_t)key*KVD + 32 + g*8);
#pragma unroll
      for (int m=0;m<2;m++){
        f32x4 z = (f32x4){0.f,0.f,0.f,0.f};
        z = mfma_bf16(qf[m][0], kf0, z);
        sc[m][n] = mfma_bf16(qf[m][1], kf1, z);
      }
    }
    if (cmax - cbase < 64){
#pragma unroll
      for (int n=0;n<4;n++){
        if (cbase + n*16 + r >= cmax){
#pragma unroll
          for (int m=0;m<2;m++)
#pragma unroll
            for (int j=0;j<4;j++) sc[m][n][j] = -1e30f;
        }
      }
    }
    sm_pv(sc, mrow, lrow, acc, Pw, Vsg + cbase, r, g);
  }

  // ---- diag pass: the 2 raw 64-key tiles covering this q-block ----
#pragma unroll
  for (int t=0;t<2;t++){
    const int kt = 2*qb + t;
    const int kbase = kt*64;
    const int kdb = kt*b64;
    f32x4 sc[2][4];
#pragma unroll
    for (int n=0;n<4;n++){
      const int key = kbase + n*16 + r;
      short8 kf0 = *(const short8*)(Kg + (size_t)key*KVD + g*8);
      short8 kf1 = *(const short8*)(Kg + (size_t)key*KVD + 32 + g*8);
#pragma unroll
      for (int m=0;m<2;m++){
        f32x4 z = (f32x4){0.f,0.f,0.f,0.f};
        z = mfma_bf16(qf[m][0], kf0, z);
        sc[m][n] = mfma_bf16(qf[m][1], kf1, z);
      }
    }
#pragma unroll
    for (int n=0;n<4;n++){
      const int key = kbase + n*16 + r;
      const int kd  = kdb + cd[n];
      const bool col = (cm[n] == 0);
#pragma unroll
      for (int m=0;m<2;m++)
#pragma unroll
        for (int j=0;j<4;j++){
          bool ok = (key <= qv[m][j]) && (col || (kd == qd[m][j]));
          sc[m][n][j] = ok ? sc[m][n][j] : -1e30f;
        }
    }
    sm_pv(sc, mrow, lrow, acc, Pw, Vdg + kbase, r, g);
  }

  // epilogue: O /= l, write bf16
#pragma unroll
  for (int m=0;m<2;m++)
#pragma unroll
    for (int j=0;j<4;j++){
      float inv = 1.f / lrow[m][j];
      int q = qv[m][j];
#pragma unroll
      for (int f=0;f<4;f++)
        Ob[(size_t)q*NHD + h*HD + f*16 + r] = f2bf(acc[m][f][j]*inv);
    }
}

// ---------------- launch ----------------
extern "C" void kernel_launch(void* const* d_in, const int* in_sizes, int n_in,
                              void* d_out, int out_size, void* d_ws, size_t ws_size,
                              hipStream_t stream){
  const float* hs   = (const float*)d_in[0];
  const float* cosT = (const float*)d_in[1];
  const float* sinT = (const float*)d_in[2];
  const float* Wq   = (const float*)d_in[3];
  const float* Wk   = (const float*)d_in[4];
  const float* Wv   = (const float*)d_in[5];
  const float* Wo   = (const float*)d_in[6];
  const int*   nm   = (const int*)d_in[7];

  char* ws = (char*)d_ws;
  short* hsb  = (short*)(ws);                   // 8 MB
  short* WqT  = (short*)(ws + (8ull<<20));      // 8 MB
  short* WkT  = (short*)(ws + (16ull<<20));     // 2 MB
  short* WvT  = (short*)(ws + (18ull<<20));     // 2 MB
  short* WoT  = (short*)(ws + (20ull<<20));     // 8 MB
  float* Qf   = (float*)(ws + (28ull<<20));     // 16 MB
  float* Kf   = (float*)(ws + (44ull<<20));     // 4 MB (reused as VTs after rope-K)
  short* VTs  = (short*)(ws + (44ull<<20));     // 2 MB (aliases Kf; written after rope-K)
  float* Vf   = (float*)(ws + (48ull<<20));     // 4 MB
  short* Qb   = (short*)(ws + (52ull<<20));     // 8 MB
  short* Kb   = (short*)(ws + (60ull<<20));     // 2 MB
  short* VT   = (short*)(ws + (62ull<<20));     // 2 MB
  short* attnb= (short*)(ws + (64ull<<20));     // 8 MB
  float* out  = (float*)d_out;

  k_f32_to_bf16<<<(S_LEN*HIDDEN/4+255)/256, 256, 0, stream>>>(hs, hsb, S_LEN*HIDDEN/4);
  k_transpose<<<dim3(NHD/32, HIDDEN/32), 256, 0, stream>>>(Wq, WqT, HIDDEN, NHD);
  k_transpose<<<dim3(KVD/32, HIDDEN/32), 256, 0, stream>>>(Wk, WkT, HIDDEN, KVD);
  k_transpose<<<dim3(KVD/32, HIDDEN/32), 256, 0, stream>>>(Wv, WvT, HIDDEN, KVD);
  k_transpose<<<dim3(HIDDEN/32, NHD/32), 256, 0, stream>>>(Wo, WoT, NHD, HIDDEN);

  k_gemm_qkv<<<dim3(48, 16), 256, 0, stream>>>(hsb, WqT, WkT, WvT, Qf, Kf, Vf);

  k_rope<<<(S_LEN*NH*32)/256, 256, 0, stream>>>(Qf, cosT, sinT, Qb, 5, 0.125f);
  k_rope<<<(S_LEN*NKVH*32)/256, 256, 0, stream>>>(Kf, cosT, sinT, Kb, 3, 1.0f);

  k_transpose<<<dim3(KVD/32, S_LEN/32), 256, 0, stream>>>(Vf, VT, S_LEN, KVD);
  k_vt_sparse<<<dim3(S_LEN/32, KVD/32), 256, 0, stream>>>(Vf, VTs, nm);

  k_attn2<<<dim3(S_LEN/128, NH), 256, 0, stream>>>(Qb, Kb, VT, VTs, nm, attnb);

  k_gemm<<<dim3(32, 16), 256, 0, stream>>>(attnb, WoT, out, HIDDEN);
}

// Round 4
// 165.627 us; speedup vs baseline: 1.8372x; 1.0712x over previous
//
#include <hip/hip_runtime.h>
#include <hip/hip_bf16.h>
#include <stdint.h>

#define S_LEN  2048
#define HIDDEN 2048
#define NH     32
#define NKVH   8
#define HD     64
#define NHD    (NH*HD)    // 2048
#define KVD    (NKVH*HD)  // 512

typedef __attribute__((ext_vector_type(8))) short  short8;
typedef __attribute__((ext_vector_type(4))) short  short4v;
typedef __attribute__((ext_vector_type(4))) float  f32x4;
typedef __attribute__((ext_vector_type(4))) float  float4v;
typedef __attribute__((ext_vector_type(8))) __bf16 bf16x8;

__device__ __forceinline__ short f2bf(float x){
  uint32_t u = __builtin_bit_cast(uint32_t, x);
  u += 0x7fffu + ((u >> 16) & 1u);   // RNE; inputs are finite
  return (short)(u >> 16);
}

__device__ __forceinline__ f32x4 mfma_bf16(short8 a, short8 b, f32x4 c){
  return __builtin_amdgcn_mfma_f32_16x16x32_bf16(
      __builtin_bit_cast(bf16x8, a), __builtin_bit_cast(bf16x8, b), c, 0, 0, 0);
}

// async global->LDS, 16B per lane; LDS dest = wave-uniform base + lane*16
__device__ __forceinline__ void gload16(const short* g, short* l){
  __builtin_amdgcn_global_load_lds(
      (const __attribute__((address_space(1))) void*)g,
      (__attribute__((address_space(3))) void*)l, 16, 0, 0);
}

// ---------------- elementwise fp32 -> bf16 ----------------
__global__ __launch_bounds__(256) void k_f32_to_bf16(const float* __restrict__ X,
                                                     short* __restrict__ Y, int n4){
  int i = blockIdx.x*256 + threadIdx.x;
  if (i >= n4) return;
  float4v v = ((const float4v* __restrict__)X)[i];
  short4v o;
#pragma unroll
  for (int j=0;j<4;j++) o[j] = f2bf(v[j]);
  ((short4v* __restrict__)Y)[i] = o;
}

// ---------------- transpose fp32 (R x C) -> bf16 (C x R) ----------------
__global__ __launch_bounds__(256) void k_transpose(const float* __restrict__ W,
                                                   short* __restrict__ WT, int R, int C){
  __shared__ float tile[32][33];
  int x = threadIdx.x & 31, y0 = threadIdx.x >> 5;
  int c0 = blockIdx.x*32, r0 = blockIdx.y*32;
#pragma unroll
  for (int yy=y0; yy<32; yy+=8) tile[yy][x] = W[(size_t)(r0+yy)*C + c0 + x];
  __syncthreads();
#pragma unroll
  for (int yy=y0; yy<32; yy+=8) WT[(size_t)(c0+yy)*R + r0 + x] = f2bf(tile[x][yy]);
}

// ---------------- transpose bf16 (R x C) -> bf16 (C x R) ----------------
__global__ __launch_bounds__(256) void k_transpose_bb(const short* __restrict__ V,
                                                      short* __restrict__ VT, int R, int C){
  __shared__ short tile[32][33];
  int x = threadIdx.x & 31, y0 = threadIdx.x >> 5;
  int c0 = blockIdx.x*32, r0 = blockIdx.y*32;
#pragma unroll
  for (int yy=y0; yy<32; yy+=8) tile[yy][x] = V[(size_t)(r0+yy)*C + c0 + x];
  __syncthreads();
#pragma unroll
  for (int yy=y0; yy<32; yy+=8) VT[(size_t)(c0+yy)*R + r0 + x] = tile[x][yy];
}

// ---- sparse-column V transpose (bf16 in): VTs[d][c] = V[bs*c][d] ----
__global__ __launch_bounds__(256) void k_vt_sparse_bb(const short* __restrict__ V,
                                                      short* __restrict__ VTs,
                                                      const int* __restrict__ nm){
  int bs = nm[0] + 1;
  int Sc = S_LEN / bs;
  __shared__ short tile[32][33];
  int x = threadIdx.x & 31, y0 = threadIdx.x >> 5;
  int c0 = blockIdx.x*32, d0 = blockIdx.y*32;
  if (c0 >= Sc) return;
#pragma unroll
  for (int yy=y0; yy<32; yy+=8) tile[yy][x] = V[(size_t)(bs*(c0+yy))*KVD + d0 + x];
  __syncthreads();
#pragma unroll
  for (int yy=y0; yy<32; yy+=8) VTs[(size_t)(d0+yy)*S_LEN + c0 + x] = tile[x][yy];
}

// ==== pipelined GEMM core: acc[4][4] += A[M,K] * BT[N,K]^T over one 128x128 tile
// T3-minimum 2-phase: STAGE(next buf) issued BEFORE ds_read+MFMA(cur buf);
// one vmcnt(0)+barrier per K-step (the __syncthreads drain). Static dbuf unroll.
struct GemmIdx {
  int wid, r, g, wr, wc, srow, scol;
};
__device__ __forceinline__ GemmIdx gemm_idx(){
  GemmIdx ix;
  int tid = threadIdx.x, lane = tid&63;
  ix.wid = tid>>6; ix.r = lane&15; ix.g = lane>>4;
  ix.wr = ix.wid>>1; ix.wc = ix.wid&1;
  ix.srow = tid>>2; ix.scol = (tid&3)*8;
  return ix;
}

__device__ __forceinline__ void stage128(const short* gA, const short* gB,
                                         short* As, short* Bs, int kt, int wid){
  const int K = HIDDEN;
  gload16(gA + kt*32,              As + wid*512);
  gload16(gA + (size_t)64*K + kt*32, As + 2048 + wid*512);
  gload16(gB + kt*32,              Bs + wid*512);
  gload16(gB + (size_t)64*K + kt*32, Bs + 2048 + wid*512);
}

__device__ __forceinline__ void compute128(const short* As, const short* Bs,
                                           f32x4 acc[4][4], const GemmIdx& ix){
  short8 af[4], bf[4];
#pragma unroll
  for (int m=0;m<4;m++) af[m] = *(const short8*)&As[(ix.wr*64 + m*16 + ix.r)*32 + ix.g*8];
#pragma unroll
  for (int n=0;n<4;n++) bf[n] = *(const short8*)&Bs[(ix.wc*64 + n*16 + ix.r)*32 + ix.g*8];
#pragma unroll
  for (int m=0;m<4;m++)
#pragma unroll
    for (int n=0;n<4;n++) acc[m][n] = mfma_bf16(af[m], bf[n], acc[m][n]);
}

__device__ __forceinline__ void gemm_core(const short* __restrict__ A,
                                          const short* __restrict__ BT,
                                          int bm, int bn,
                                          short* As0, short* Bs0,
                                          short* As1, short* Bs1,
                                          f32x4 acc[4][4], const GemmIdx& ix){
  const int K = HIDDEN;
  const short* gA = A  + (size_t)(bm*128 + ix.srow)*K + ix.scol;
  const short* gB = BT + (size_t)(bn*128 + ix.srow)*K + ix.scol;

#pragma unroll
  for (int m=0;m<4;m++)
#pragma unroll
    for (int n=0;n<4;n++) acc[m][n] = (f32x4){0.f,0.f,0.f,0.f};

  const int nkt = K/32;                 // 64 (even)
  stage128(gA, gB, As0, Bs0, 0, ix.wid);
  __syncthreads();                      // vmcnt(0)+barrier: buf0 ready
  for (int u=0; u<nkt/2; ++u){
    const int t = 2*u;
    if (t+1 < nkt) stage128(gA, gB, As1, Bs1, t+1, ix.wid);  // in flight
    compute128(As0, Bs0, acc, ix);
    __syncthreads();                    // buf1 landed; buf0 free
    if (t+2 < nkt) stage128(gA, gB, As0, Bs0, t+2, ix.wid);
    compute128(As1, Bs1, acc, ix);
    __syncthreads();
  }
}

// QKV GEMM with fused RoPE + scale + bf16 epilogue.
// bn<16: Q -> Qb (roped, *0.125); bn 16..19: K -> Kb (roped); bn 20..23: V -> Vb.
__global__ __launch_bounds__(256) void k_gemm_qkv(const short* __restrict__ hsb,
                                                  const short* __restrict__ WqT,
                                                  const short* __restrict__ WkT,
                                                  const short* __restrict__ WvT,
                                                  const float* __restrict__ cosT,
                                                  const float* __restrict__ sinT,
                                                  short* __restrict__ Qb,
                                                  short* __restrict__ Kb,
                                                  short* __restrict__ Vb){
  __shared__ short As0[128*32], Bs0[128*32], As1[128*32], Bs1[128*32];
  const int bn = blockIdx.x, bm = blockIdx.y;
  GemmIdx ix = gemm_idx();
  f32x4 acc[4][4];

  if (bn < 16){
    gemm_core(hsb, WqT + (size_t)bn*128*HIDDEN, bm, 0, As0, Bs0, As1, Bs1, acc, ix);
    const int h2 = bn*2 + ix.wc;
#pragma unroll
    for (int m=0;m<4;m++)
#pragma unroll
      for (int j=0;j<4;j++){
        const int s = bm*128 + ix.wr*64 + m*16 + ix.g*4 + j;
        const float* cr = cosT + s*64;
        const float* sr = sinT + s*64;
#pragma unroll
        for (int n=0;n<2;n++){
          const int d = n*16 + ix.r;
          float x1 = acc[m][n][j], x2 = acc[m][n+2][j];
          Qb[(size_t)s*NHD + h2*64 + d]      = f2bf((x1*cr[d]    - x2*sr[d])   *0.125f);
          Qb[(size_t)s*NHD + h2*64 + d + 32] = f2bf((x2*cr[d+32] + x1*sr[d+32])*0.125f);
        }
      }
  } else if (bn < 20){
    gemm_core(hsb, WkT + (size_t)(bn-16)*128*HIDDEN, bm, 0, As0, Bs0, As1, Bs1, acc, ix);
    const int h2 = (bn-16)*2 + ix.wc;
#pragma unroll
    for (int m=0;m<4;m++)
#pragma unroll
      for (int j=0;j<4;j++){
        const int s = bm*128 + ix.wr*64 + m*16 + ix.g*4 + j;
        const float* cr = cosT + s*64;
        const float* sr = sinT + s*64;
#pragma unroll
        for (int n=0;n<2;n++){
          const int d = n*16 + ix.r;
          float x1 = acc[m][n][j], x2 = acc[m][n+2][j];
          Kb[(size_t)s*KVD + h2*64 + d]      = f2bf(x1*cr[d]    - x2*sr[d]);
          Kb[(size_t)s*KVD + h2*64 + d + 32] = f2bf(x2*cr[d+32] + x1*sr[d+32]);
        }
      }
  } else {
    gemm_core(hsb, WvT + (size_t)(bn-20)*128*HIDDEN, bm, 0, As0, Bs0, As1, Bs1, acc, ix);
    const int c0 = (bn-20)*128 + ix.wc*64;
#pragma unroll
    for (int m=0;m<4;m++)
#pragma unroll
      for (int n=0;n<4;n++)
#pragma unroll
        for (int j=0;j<4;j++){
          const int s = bm*128 + ix.wr*64 + m*16 + ix.g*4 + j;
          Vb[(size_t)s*KVD + c0 + n*16 + ix.r] = f2bf(acc[m][n][j]);
        }
  }
}

// generic pipelined GEMM, fp32 output
__global__ __launch_bounds__(256) void k_gemm(const short* __restrict__ A,
                                              const short* __restrict__ BT,
                                              float* __restrict__ C, int Nc){
  __shared__ short As0[128*32], Bs0[128*32], As1[128*32], Bs1[128*32];
  const int bn = blockIdx.x, bm = blockIdx.y;
  GemmIdx ix = gemm_idx();
  f32x4 acc[4][4];
  gemm_core(A, BT, bm, bn, As0, Bs0, As1, Bs1, acc, ix);
#pragma unroll
  for (int m=0;m<4;m++)
#pragma unroll
    for (int n=0;n<4;n++)
#pragma unroll
      for (int j=0;j<4;j++)
        C[(size_t)(bm*128 + ix.wr*64 + m*16 + ix.g*4 + j)*Nc
          + bn*128 + ix.wc*64 + n*16 + ix.r] = acc[m][n][j];
}

// ---------------- attention: shared softmax/PV tail for one 64-key tile --------
__device__ __forceinline__ void sm_pv(f32x4 sc[2][4],
                                      float mrow[2][4], float lrow[2][4],
                                      f32x4 acc[2][4], short* Pw,
                                      const short* Vtile,   // [d][col], stride S_LEN
                                      int r, int g){
#pragma unroll
  for (int m=0;m<2;m++){
#pragma unroll
    for (int j=0;j<4;j++){
      float v = fmaxf(fmaxf(sc[m][0][j], sc[m][1][j]), fmaxf(sc[m][2][j], sc[m][3][j]));
      v = fmaxf(v, __shfl_xor(v, 1));
      v = fmaxf(v, __shfl_xor(v, 2));
      v = fmaxf(v, __shfl_xor(v, 4));
      v = fmaxf(v, __shfl_xor(v, 8));
      float mn = fmaxf(mrow[m][j], v);
      float fac = __expf(mrow[m][j] - mn);
      mrow[m][j] = mn;
#pragma unroll
      for (int f=0;f<4;f++) acc[m][f][j] *= fac;
      float rs = 0.f;
#pragma unroll
      for (int n=0;n<4;n++){
        float p = __expf(sc[m][n][j] - mn);
        rs += p;
        sc[m][n][j] = p;
      }
      rs += __shfl_xor(rs, 1);
      rs += __shfl_xor(rs, 2);
      rs += __shfl_xor(rs, 4);
      rs += __shfl_xor(rs, 8);
      lrow[m][j] = lrow[m][j]*fac + rs;
    }
  }
  // P -> per-wave LDS (bf16), C-layout write, A-layout read (same wave: lgkm only)
#pragma unroll
  for (int m=0;m<2;m++)
#pragma unroll
    for (int n=0;n<4;n++)
#pragma unroll
      for (int j=0;j<4;j++)
        Pw[(m*16 + g*4 + j)*72 + n*16 + r] = f2bf(sc[m][n][j]);

  short8 pf[2][2];
#pragma unroll
  for (int m=0;m<2;m++)
#pragma unroll
    for (int kk=0;kk<2;kk++)
      pf[m][kk] = *(short8*)&Pw[(m*16 + r)*72 + kk*32 + g*8];

#pragma unroll
  for (int f=0;f<4;f++){
#pragma unroll
    for (int kk=0;kk<2;kk++){
      short8 vf = *(const short8*)(Vtile + (size_t)(f*16 + r)*S_LEN + kk*32 + g*8);
#pragma unroll
      for (int m=0;m<2;m++)
        acc[m][f] = mfma_bf16(pf[m][kk], vf, acc[m][f]);
    }
  }
}

// 128 q-rows/block, 4 independent waves (32 rows each), no barriers in loop.
__global__ __launch_bounds__(256) void k_attn2(const short* __restrict__ Qb,
                                               const short* __restrict__ Kb,   // [S][KVD]
                                               const short* __restrict__ VT,   // [KVD][S]
                                               const short* __restrict__ VTs,  // [KVD][S/bs], stride S
                                               const int* __restrict__ nm,
                                               short* __restrict__ Ob){
  const int qb = gridDim.x - 1 - blockIdx.x;   // heavy q-blocks first
  const int h  = blockIdx.y;
  const int hk = h >> 2;
  const int bs = nm[0] + 1;                    // requires bs | 64

  const int tid = threadIdx.x, wid = tid>>6, lane = tid&63;
  const int r = lane&15, g = lane>>4;

  __shared__ short P_lds[4][32*72];
  short* Pw = &P_lds[wid][0];

  const int qlo = qb*128;
  const int rowbase = qlo + wid*32;

  short8 qf[2][2];
#pragma unroll
  for (int m=0;m<2;m++)
#pragma unroll
    for (int kk=0;kk<2;kk++)
      qf[m][kk] = *(const short8*)(Qb + (size_t)(rowbase + m*16 + r)*NHD + h*HD + kk*32 + g*8);

  f32x4 acc[2][4];
  float mrow[2][4], lrow[2][4];
#pragma unroll
  for (int m=0;m<2;m++){
#pragma unroll
    for (int f=0;f<4;f++) acc[m][f] = (f32x4){0.f,0.f,0.f,0.f};
#pragma unroll
    for (int j=0;j<4;j++){ mrow[m][j] = -1e30f; lrow[m][j] = 0.f; }
  }

  const int b64 = 64/bs;
  int cd[4], cm[4];
#pragma unroll
  for (int n=0;n<4;n++){ int c = n*16 + r; cd[n] = c/bs; cm[n] = c%bs; }
  int qv[2][4], qd[2][4];
  const int qdbase = qlo/bs;
#pragma unroll
  for (int m=0;m<2;m++)
#pragma unroll
    for (int j=0;j<4;j++){
      int qrel = wid*32 + m*16 + g*4 + j;
      qv[m][j] = qlo + qrel;
      qd[m][j] = qdbase + qrel/bs;
    }

  const short* Kg  = Kb  + hk*HD;
  const short* Vsg = VTs + (size_t)hk*HD*S_LEN;
  const short* Vdg = VT  + (size_t)hk*HD*S_LEN;

  // ---- column pass: keys k = bs*c, c < cmax, all allowed ----
  const int cmax = qlo / bs;
  const int nct = (cmax + 63) >> 6;
  for (int ct=0; ct<nct; ++ct){
    const int cbase = ct*64;
    f32x4 sc[2][4];
#pragma unroll
    for (int n=0;n<4;n++){
      const int key = bs*(cbase + n*16 + r);
      short8 kf0 = *(const short8*)(Kg + (size_t)key*KVD + g*8);
      short8 kf1 = *(const short8*)(Kg + (size_t)key*KVD + 32 + g*8);
#pragma unroll
      for (int m=0;m<2;m++){
        f32x4 z = (f32x4){0.f,0.f,0.f,0.f};
        z = mfma_bf16(qf[m][0], kf0, z);
        sc[m][n] = mfma_bf16(qf[m][1], kf1, z);
      }
    }
    if (cmax - cbase < 64){
#pragma unroll
      for (int n=0;n<4;n++){
        if (cbase + n*16 + r >= cmax){
#pragma unroll
          for (int m=0;m<2;m++)
#pragma unroll
            for (int j=0;j<4;j++) sc[m][n][j] = -1e30f;
        }
      }
    }
    sm_pv(sc, mrow, lrow, acc, Pw, Vsg + cbase, r, g);
  }

  // ---- diag pass: the 2 raw 64-key tiles covering this q-block ----
#pragma unroll
  for (int t=0;t<2;t++){
    const int kt = 2*qb + t;
    const int kbase = kt*64;
    const int kdb = kt*b64;
    f32x4 sc[2][4];
#pragma unroll
    for (int n=0;n<4;n++){
      const int key = kbase + n*16 + r;
      short8 kf0 = *(const short8*)(Kg + (size_t)key*KVD + g*8);
      short8 kf1 = *(const short8*)(Kg + (size_t)key*KVD + 32 + g*8);
#pragma unroll
      for (int m=0;m<2;m++){
        f32x4 z = (f32x4){0.f,0.f,0.f,0.f};
        z = mfma_bf16(qf[m][0], kf0, z);
        sc[m][n] = mfma_bf16(qf[m][1], kf1, z);
      }
    }
#pragma unroll
    for (int n=0;n<4;n++){
      const int key = kbase + n*16 + r;
      const int kd  = kdb + cd[n];
      const bool col = (cm[n] == 0);
#pragma unroll
      for (int m=0;m<2;m++)
#pragma unroll
        for (int j=0;j<4;j++){
          bool ok = (key <= qv[m][j]) && (col || (kd == qd[m][j]));
          sc[m][n][j] = ok ? sc[m][n][j] : -1e30f;
        }
    }
    sm_pv(sc, mrow, lrow, acc, Pw, Vdg + kbase, r, g);
  }

  // epilogue: O /= l, write bf16
#pragma unroll
  for (int m=0;m<2;m++)
#pragma unroll
    for (int j=0;j<4;j++){
      float inv = 1.f / lrow[m][j];
      int q = qv[m][j];
#pragma unroll
      for (int f=0;f<4;f++)
        Ob[(size_t)q*NHD + h*HD + f*16 + r] = f2bf(acc[m][f][j]*inv);
    }
}

// ---------------- launch ----------------
extern "C" void kernel_launch(void* const* d_in, const int* in_sizes, int n_in,
                              void* d_out, int out_size, void* d_ws, size_t ws_size,
                              hipStream_t stream){
  const float* hs   = (const float*)d_in[0];
  const float* cosT = (const float*)d_in[1];
  const float* sinT = (const float*)d_in[2];
  const float* Wq   = (const float*)d_in[3];
  const float* Wk   = (const float*)d_in[4];
  const float* Wv   = (const float*)d_in[5];
  const float* Wo   = (const float*)d_in[6];
  const int*   nm   = (const int*)d_in[7];

  char* ws = (char*)d_ws;
  short* hsb  = (short*)(ws);                   // 8 MB
  short* WqT  = (short*)(ws + (8ull<<20));      // 8 MB
  short* WkT  = (short*)(ws + (16ull<<20));     // 2 MB
  short* WvT  = (short*)(ws + (18ull<<20));     // 2 MB
  short* WoT  = (short*)(ws + (20ull<<20));     // 8 MB
  short* Qb   = (short*)(ws + (28ull<<20));     // 8 MB
  short* Kb   = (short*)(ws + (36ull<<20));     // 2 MB
  short* Vb   = (short*)(ws + (38ull<<20));     // 2 MB
  short* VT   = (short*)(ws + (40ull<<20));     // 2 MB
  short* VTs  = (short*)(ws + (42ull<<20));     // 2 MB
  short* attnb= (short*)(ws + (44ull<<20));     // 8 MB
  float* out  = (float*)d_out;

  k_f32_to_bf16<<<(S_LEN*HIDDEN/4+255)/256, 256, 0, stream>>>(hs, hsb, S_LEN*HIDDEN/4);
  k_transpose<<<dim3(NHD/32, HIDDEN/32), 256, 0, stream>>>(Wq, WqT, HIDDEN, NHD);
  k_transpose<<<dim3(KVD/32, HIDDEN/32), 256, 0, stream>>>(Wk, WkT, HIDDEN, KVD);
  k_transpose<<<dim3(KVD/32, HIDDEN/32), 256, 0, stream>>>(Wv, WvT, HIDDEN, KVD);
  k_transpose<<<dim3(HIDDEN/32, NHD/32), 256, 0, stream>>>(Wo, WoT, NHD, HIDDEN);

  // QKV GEMM + fused RoPE/scale/bf16 epilogue
  k_gemm_qkv<<<dim3(24, 16), 256, 0, stream>>>(hsb, WqT, WkT, WvT, cosT, sinT,
                                               Qb, Kb, Vb);

  k_transpose_bb<<<dim3(KVD/32, S_LEN/32), 256, 0, stream>>>(Vb, VT, S_LEN, KVD);
  k_vt_sparse_bb<<<dim3(S_LEN/32, KVD/32), 256, 0, stream>>>(Vb, VTs, nm);

  k_attn2<<<dim3(S_LEN/128, NH), 256, 0, stream>>>(Qb, Kb, VT, VTs, nm, attnb);

  k_gemm<<<dim3(NHD/128, S_LEN/128), 256, 0, stream>>>(attnb, WoT, out, HIDDEN);
}

// Round 5
// 151.779 us; speedup vs baseline: 2.0048x; 1.0912x over previous
//
#include <hip/hip_runtime.h>
#include <hip/hip_bf16.h>
#include <stdint.h>

#define S_LEN  2048
#define HIDDEN 2048
#define NH     32
#define NKVH   8
#define HD     64
#define NHD    (NH*HD)    // 2048
#define KVD    (NKVH*HD)  // 512

typedef __attribute__((ext_vector_type(8))) short  short8;
typedef __attribute__((ext_vector_type(4))) short  short4v;
typedef __attribute__((ext_vector_type(4))) float  f32x4;
typedef __attribute__((ext_vector_type(4))) float  float4v;
typedef __attribute__((ext_vector_type(8))) __bf16 bf16x8;

__device__ __forceinline__ short f2bf(float x){
  uint32_t u = __builtin_bit_cast(uint32_t, x);
  u += 0x7fffu + ((u >> 16) & 1u);   // RNE; inputs are finite
  return (short)(u >> 16);
}

__device__ __forceinline__ f32x4 mfma_bf16(short8 a, short8 b, f32x4 c){
  return __builtin_amdgcn_mfma_f32_16x16x32_bf16(
      __builtin_bit_cast(bf16x8, a), __builtin_bit_cast(bf16x8, b), c, 0, 0, 0);
}

// async global->LDS, 16B per lane; LDS dest = wave-uniform base + lane*16
__device__ __forceinline__ void gload16(const short* g, short* l){
  __builtin_amdgcn_global_load_lds(
      (const __attribute__((address_space(1))) void*)g,
      (__attribute__((address_space(3))) void*)l, 16, 0, 0);
}

// ---------------- elementwise fp32 -> bf16 ----------------
__global__ __launch_bounds__(256) void k_f32_to_bf16(const float* __restrict__ X,
                                                     short* __restrict__ Y, int n4){
  int i = blockIdx.x*256 + threadIdx.x;
  if (i >= n4) return;
  float4v v = ((const float4v* __restrict__)X)[i];
  short4v o;
#pragma unroll
  for (int j=0;j<4;j++) o[j] = f2bf(v[j]);
  ((short4v* __restrict__)Y)[i] = o;
}

// ---------------- transpose fp32 (R x C) -> bf16 (C x R) ----------------
__global__ __launch_bounds__(256) void k_transpose(const float* __restrict__ W,
                                                   short* __restrict__ WT, int R, int C){
  __shared__ float tile[32][33];
  int x = threadIdx.x & 31, y0 = threadIdx.x >> 5;
  int c0 = blockIdx.x*32, r0 = blockIdx.y*32;
#pragma unroll
  for (int yy=y0; yy<32; yy+=8) tile[yy][x] = W[(size_t)(r0+yy)*C + c0 + x];
  __syncthreads();
#pragma unroll
  for (int yy=y0; yy<32; yy+=8) WT[(size_t)(c0+yy)*R + r0 + x] = f2bf(tile[x][yy]);
}

// ---------------- transpose bf16 (R x C) -> bf16 (C x R) ----------------
__global__ __launch_bounds__(256) void k_transpose_bb(const short* __restrict__ V,
                                                      short* __restrict__ VT, int R, int C){
  __shared__ short tile[32][33];
  int x = threadIdx.x & 31, y0 = threadIdx.x >> 5;
  int c0 = blockIdx.x*32, r0 = blockIdx.y*32;
#pragma unroll
  for (int yy=y0; yy<32; yy+=8) tile[yy][x] = V[(size_t)(r0+yy)*C + c0 + x];
  __syncthreads();
#pragma unroll
  for (int yy=y0; yy<32; yy+=8) VT[(size_t)(c0+yy)*R + r0 + x] = tile[x][yy];
}

// ---- sparse-column V transpose (bf16 in): VTs[d][c] = V[bs*c][d] ----
__global__ __launch_bounds__(256) void k_vt_sparse_bb(const short* __restrict__ V,
                                                      short* __restrict__ VTs,
                                                      const int* __restrict__ nm){
  int bs = nm[0] + 1;
  int Sc = S_LEN / bs;
  __shared__ short tile[32][33];
  int x = threadIdx.x & 31, y0 = threadIdx.x >> 5;
  int c0 = blockIdx.x*32, d0 = blockIdx.y*32;
  if (c0 >= Sc) return;
#pragma unroll
  for (int yy=y0; yy<32; yy+=8) tile[yy][x] = V[(size_t)(bs*(c0+yy))*KVD + d0 + x];
  __syncthreads();
#pragma unroll
  for (int yy=y0; yy<32; yy+=8) VTs[(size_t)(d0+yy)*S_LEN + c0 + x] = tile[x][yy];
}

// ==== 512-thread in-block split-K GEMM core =====================================
// 8 waves: group kg=0 computes K[0,1024), kg=1 computes K[1024,2048), each group
// has its own double-buffered LDS pipeline (2-phase: STAGE(next) issued before
// compute(cur), one vmcnt(0)+barrier per K-step). Cross-group reduce via LDS at
// the end; group 0 holds the full sum and runs the epilogue.
struct GemmIdx {
  int wid, r, g, wr, wc, kg, gtid;
};
__device__ __forceinline__ GemmIdx gemm_idx(){
  GemmIdx ix;
  int tid = threadIdx.x, lane = tid&63;
  ix.kg = tid>>8; ix.gtid = tid&255;
  ix.wid = (tid>>6)&3; ix.r = lane&15; ix.g = lane>>4;
  ix.wr = ix.wid>>1; ix.wc = ix.wid&1;
  return ix;
}

__device__ __forceinline__ void stage128(const short* gA, const short* gB,
                                         short* As, short* Bs, int kt, int w){
  const int K = HIDDEN;
  gload16(gA + kt*32,                As + w*512);
  gload16(gA + (size_t)64*K + kt*32, As + 2048 + w*512);
  gload16(gB + kt*32,                Bs + w*512);
  gload16(gB + (size_t)64*K + kt*32, Bs + 2048 + w*512);
}

__device__ __forceinline__ void compute128(const short* As, const short* Bs,
                                           f32x4 acc[4][4], const GemmIdx& ix){
  short8 af[4], bf[4];
#pragma unroll
  for (int m=0;m<4;m++) af[m] = *(const short8*)&As[(ix.wr*64 + m*16 + ix.r)*32 + ix.g*8];
#pragma unroll
  for (int n=0;n<4;n++) bf[n] = *(const short8*)&Bs[(ix.wc*64 + n*16 + ix.r)*32 + ix.g*8];
#pragma unroll
  for (int m=0;m<4;m++)
#pragma unroll
    for (int n=0;n<4;n++) acc[m][n] = mfma_bf16(af[m], bf[n], acc[m][n]);
}

// LDS: 32768 shorts (64 KB). Group kg uses shorts [kg*16384, kg*16384+16384):
// As0/Bs0/As1/Bs1 of 4096 shorts each. After the loop the whole 64 KB is reused
// as fp32 reduce scratch (4 quadrants x 64x64 f32 = 64 KB exactly).
__device__ __forceinline__ void gemm_core512(const short* __restrict__ A,
                                             const short* __restrict__ BT,
                                             int bm, int bn, short* LDS,
                                             f32x4 acc[4][4], const GemmIdx& ix){
  const int K = HIDDEN;
  const short* gA = A  + (size_t)(bm*128 + (ix.gtid>>2))*K + ix.kg*1024 + (ix.gtid&3)*8;
  const short* gB = BT + (size_t)(bn*128 + (ix.gtid>>2))*K + ix.kg*1024 + (ix.gtid&3)*8;
  short* L   = LDS + ix.kg*16384;
  short* As0 = L;        short* Bs0 = L + 4096;
  short* As1 = L + 8192; short* Bs1 = L + 12288;
  const int w = ix.gtid>>6;

#pragma unroll
  for (int m=0;m<4;m++)
#pragma unroll
    for (int n=0;n<4;n++) acc[m][n] = (f32x4){0.f,0.f,0.f,0.f};

  const int nkt = 32;                   // K=1024 per group, BK=32
  stage128(gA, gB, As0, Bs0, 0, w);
  __syncthreads();                      // buf0 ready (vmcnt(0)+barrier)
  for (int u=0; u<nkt/2; ++u){
    const int t = 2*u;
    if (t+1 < nkt) stage128(gA, gB, As1, Bs1, t+1, w);   // in flight under compute
    compute128(As0, Bs0, acc, ix);
    __syncthreads();                    // buf1 landed; buf0 free
    if (t+2 < nkt) stage128(gA, gB, As0, Bs0, t+2, w);
    compute128(As1, Bs1, acc, ix);
    __syncthreads();
  }

  // cross-group reduce: group1 -> LDS, group0 adds
  float* red = (float*)LDS;
  if (ix.kg){
#pragma unroll
    for (int m=0;m<4;m++)
#pragma unroll
      for (int n=0;n<4;n++)
#pragma unroll
        for (int j=0;j<4;j++)
          red[ix.wid*4096 + (m*16 + ix.g*4 + j)*64 + n*16 + ix.r] = acc[m][n][j];
  }
  __syncthreads();
  if (!ix.kg){
#pragma unroll
    for (int m=0;m<4;m++)
#pragma unroll
      for (int n=0;n<4;n++)
#pragma unroll
        for (int j=0;j<4;j++)
          acc[m][n][j] += red[ix.wid*4096 + (m*16 + ix.g*4 + j)*64 + n*16 + ix.r];
  }
}

// QKV GEMM with fused RoPE + scale + bf16 epilogue (group 0 only).
__global__ __launch_bounds__(512, 4) void k_gemm_qkv(const short* __restrict__ hsb,
                                                     const short* __restrict__ WqT,
                                                     const short* __restrict__ WkT,
                                                     const short* __restrict__ WvT,
                                                     const float* __restrict__ cosT,
                                                     const float* __restrict__ sinT,
                                                     short* __restrict__ Qb,
                                                     short* __restrict__ Kb,
                                                     short* __restrict__ Vb){
  __shared__ short LDS[32768];
  const int bn = blockIdx.x, bm = blockIdx.y;
  GemmIdx ix = gemm_idx();
  f32x4 acc[4][4];

  if (bn < 16){
    gemm_core512(hsb, WqT + (size_t)bn*128*HIDDEN, bm, 0, LDS, acc, ix);
    if (ix.kg) return;
    const int h2 = bn*2 + ix.wc;
#pragma unroll
    for (int m=0;m<4;m++)
#pragma unroll
      for (int j=0;j<4;j++){
        const int s = bm*128 + ix.wr*64 + m*16 + ix.g*4 + j;
        const float* cr = cosT + s*64;
        const float* sr = sinT + s*64;
#pragma unroll
        for (int n=0;n<2;n++){
          const int d = n*16 + ix.r;
          float x1 = acc[m][n][j], x2 = acc[m][n+2][j];
          Qb[(size_t)s*NHD + h2*64 + d]      = f2bf((x1*cr[d]    - x2*sr[d])   *0.125f);
          Qb[(size_t)s*NHD + h2*64 + d + 32] = f2bf((x2*cr[d+32] + x1*sr[d+32])*0.125f);
        }
      }
  } else if (bn < 20){
    gemm_core512(hsb, WkT + (size_t)(bn-16)*128*HIDDEN, bm, 0, LDS, acc, ix);
    if (ix.kg) return;
    const int h2 = (bn-16)*2 + ix.wc;
#pragma unroll
    for (int m=0;m<4;m++)
#pragma unroll
      for (int j=0;j<4;j++){
        const int s = bm*128 + ix.wr*64 + m*16 + ix.g*4 + j;
        const float* cr = cosT + s*64;
        const float* sr = sinT + s*64;
#pragma unroll
        for (int n=0;n<2;n++){
          const int d = n*16 + ix.r;
          float x1 = acc[m][n][j], x2 = acc[m][n+2][j];
          Kb[(size_t)s*KVD + h2*64 + d]      = f2bf(x1*cr[d]    - x2*sr[d]);
          Kb[(size_t)s*KVD + h2*64 + d + 32] = f2bf(x2*cr[d+32] + x1*sr[d+32]);
        }
      }
  } else {
    gemm_core512(hsb, WvT + (size_t)(bn-20)*128*HIDDEN, bm, 0, LDS, acc, ix);
    if (ix.kg) return;
    const int c0 = (bn-20)*128 + ix.wc*64;
#pragma unroll
    for (int m=0;m<4;m++)
#pragma unroll
      for (int n=0;n<4;n++)
#pragma unroll
        for (int j=0;j<4;j++){
          const int s = bm*128 + ix.wr*64 + m*16 + ix.g*4 + j;
          Vb[(size_t)s*KVD + c0 + n*16 + ix.r] = f2bf(acc[m][n][j]);
        }
  }
}

// generic in-block split-K GEMM, fp32 output
__global__ __launch_bounds__(512, 4) void k_gemm(const short* __restrict__ A,
                                                 const short* __restrict__ BT,
                                                 float* __restrict__ C, int Nc){
  __shared__ short LDS[32768];
  const int bn = blockIdx.x, bm = blockIdx.y;
  GemmIdx ix = gemm_idx();
  f32x4 acc[4][4];
  gemm_core512(A, BT, bm, bn, LDS, acc, ix);
  if (ix.kg) return;
#pragma unroll
  for (int m=0;m<4;m++)
#pragma unroll
    for (int n=0;n<4;n++)
#pragma unroll
      for (int j=0;j<4;j++)
        C[(size_t)(bm*128 + ix.wr*64 + m*16 + ix.g*4 + j)*Nc
          + bn*128 + ix.wc*64 + n*16 + ix.r] = acc[m][n][j];
}

// ---------------- attention: shared softmax/PV tail for one 64-key tile --------
__device__ __forceinline__ void sm_pv(f32x4 sc[2][4],
                                      float mrow[2][4], float lrow[2][4],
                                      f32x4 acc[2][4], short* Pw,
                                      const short* Vtile,   // [d][col], stride S_LEN
                                      int r, int g){
#pragma unroll
  for (int m=0;m<2;m++){
#pragma unroll
    for (int j=0;j<4;j++){
      float v = fmaxf(fmaxf(sc[m][0][j], sc[m][1][j]), fmaxf(sc[m][2][j], sc[m][3][j]));
      v = fmaxf(v, __shfl_xor(v, 1));
      v = fmaxf(v, __shfl_xor(v, 2));
      v = fmaxf(v, __shfl_xor(v, 4));
      v = fmaxf(v, __shfl_xor(v, 8));
      float mn = fmaxf(mrow[m][j], v);
      float fac = __expf(mrow[m][j] - mn);
      mrow[m][j] = mn;
#pragma unroll
      for (int f=0;f<4;f++) acc[m][f][j] *= fac;
      float rs = 0.f;
#pragma unroll
      for (int n=0;n<4;n++){
        float p = __expf(sc[m][n][j] - mn);
        rs += p;
        sc[m][n][j] = p;
      }
      rs += __shfl_xor(rs, 1);
      rs += __shfl_xor(rs, 2);
      rs += __shfl_xor(rs, 4);
      rs += __shfl_xor(rs, 8);
      lrow[m][j] = lrow[m][j]*fac + rs;
    }
  }
  // P -> per-wave LDS (bf16), C-layout write, A-layout read (same wave: lgkm only)
#pragma unroll
  for (int m=0;m<2;m++)
#pragma unroll
    for (int n=0;n<4;n++)
#pragma unroll
      for (int j=0;j<4;j++)
        Pw[(m*16 + g*4 + j)*72 + n*16 + r] = f2bf(sc[m][n][j]);

  short8 pf[2][2];
#pragma unroll
  for (int m=0;m<2;m++)
#pragma unroll
    for (int kk=0;kk<2;kk++)
      pf[m][kk] = *(short8*)&Pw[(m*16 + r)*72 + kk*32 + g*8];

#pragma unroll
  for (int f=0;f<4;f++){
#pragma unroll
    for (int kk=0;kk<2;kk++){
      short8 vf = *(const short8*)(Vtile + (size_t)(f*16 + r)*S_LEN + kk*32 + g*8);
#pragma unroll
      for (int m=0;m<2;m++)
        acc[m][f] = mfma_bf16(pf[m][kk], vf, acc[m][f]);
    }
  }
}

// 128 q-rows/block, 4 independent waves (32 rows each), no barriers in loop.
__global__ __launch_bounds__(256) void k_attn2(const short* __restrict__ Qb,
                                               const short* __restrict__ Kb,   // [S][KVD]
                                               const short* __restrict__ VT,   // [KVD][S]
                                               const short* __restrict__ VTs,  // [KVD][S/bs], stride S
                                               const int* __restrict__ nm,
                                               short* __restrict__ Ob){
  const int qb = gridDim.x - 1 - blockIdx.x;   // heavy q-blocks first
  const int h  = blockIdx.y;
  const int hk = h >> 2;
  const int bs = nm[0] + 1;                    // requires bs | 64

  const int tid = threadIdx.x, wid = tid>>6, lane = tid&63;
  const int r = lane&15, g = lane>>4;

  __shared__ short P_lds[4][32*72];
  short* Pw = &P_lds[wid][0];

  const int qlo = qb*128;
  const int rowbase = qlo + wid*32;

  short8 qf[2][2];
#pragma unroll
  for (int m=0;m<2;m++)
#pragma unroll
    for (int kk=0;kk<2;kk++)
      qf[m][kk] = *(const short8*)(Qb + (size_t)(rowbase + m*16 + r)*NHD + h*HD + kk*32 + g*8);

  f32x4 acc[2][4];
  float mrow[2][4], lrow[2][4];
#pragma unroll
  for (int m=0;m<2;m++){
#pragma unroll
    for (int f=0;f<4;f++) acc[m][f] = (f32x4){0.f,0.f,0.f,0.f};
#pragma unroll
    for (int j=0;j<4;j++){ mrow[m][j] = -1e30f; lrow[m][j] = 0.f; }
  }

  const int b64 = 64/bs;
  int cd[4], cm[4];
#pragma unroll
  for (int n=0;n<4;n++){ int c = n*16 + r; cd[n] = c/bs; cm[n] = c%bs; }
  int qv[2][4], qd[2][4];
  const int qdbase = qlo/bs;
#pragma unroll
  for (int m=0;m<2;m++)
#pragma unroll
    for (int j=0;j<4;j++){
      int qrel = wid*32 + m*16 + g*4 + j;
      qv[m][j] = qlo + qrel;
      qd[m][j] = qdbase + qrel/bs;
    }

  const short* Kg  = Kb  + hk*HD;
  const short* Vsg = VTs + (size_t)hk*HD*S_LEN;
  const short* Vdg = VT  + (size_t)hk*HD*S_LEN;

  // ---- column pass: keys k = bs*c, c < cmax, all allowed ----
  const int cmax = qlo / bs;
  const int nct = (cmax + 63) >> 6;
  for (int ct=0; ct<nct; ++ct){
    const int cbase = ct*64;
    f32x4 sc[2][4];
#pragma unroll
    for (int n=0;n<4;n++){
      const int key = bs*(cbase + n*16 + r);
      short8 kf0 = *(const short8*)(Kg + (size_t)key*KVD + g*8);
      short8 kf1 = *(const short8*)(Kg + (size_t)key*KVD + 32 + g*8);
#pragma unroll
      for (int m=0;m<2;m++){
        f32x4 z = (f32x4){0.f,0.f,0.f,0.f};
        z = mfma_bf16(qf[m][0], kf0, z);
        sc[m][n] = mfma_bf16(qf[m][1], kf1, z);
      }
    }
    if (cmax - cbase < 64){
#pragma unroll
      for (int n=0;n<4;n++){
        if (cbase + n*16 + r >= cmax){
#pragma unroll
          for (int m=0;m<2;m++)
#pragma unroll
            for (int j=0;j<4;j++) sc[m][n][j] = -1e30f;
        }
      }
    }
    sm_pv(sc, mrow, lrow, acc, Pw, Vsg + cbase, r, g);
  }

  // ---- diag pass: the 2 raw 64-key tiles covering this q-block ----
#pragma unroll
  for (int t=0;t<2;t++){
    const int kt = 2*qb + t;
    const int kbase = kt*64;
    const int kdb = kt*b64;
    f32x4 sc[2][4];
#pragma unroll
    for (int n=0;n<4;n++){
      const int key = kbase + n*16 + r;
      short8 kf0 = *(const short8*)(Kg + (size_t)key*KVD + g*8);
      short8 kf1 = *(const short8*)(Kg + (size_t)key*KVD + 32 + g*8);
#pragma unroll
      for (int m=0;m<2;m++){
        f32x4 z = (f32x4){0.f,0.f,0.f,0.f};
        z = mfma_bf16(qf[m][0], kf0, z);
        sc[m][n] = mfma_bf16(qf[m][1], kf1, z);
      }
    }
#pragma unroll
    for (int n=0;n<4;n++){
      const int key = kbase + n*16 + r;
      const int kd  = kdb + cd[n];
      const bool col = (cm[n] == 0);
#pragma unroll
      for (int m=0;m<2;m++)
#pragma unroll
        for (int j=0;j<4;j++){
          bool ok = (key <= qv[m][j]) && (col || (kd == qd[m][j]));
          sc[m][n][j] = ok ? sc[m][n][j] : -1e30f;
        }
    }
    sm_pv(sc, mrow, lrow, acc, Pw, Vdg + kbase, r, g);
  }

  // epilogue: O /= l, write bf16
#pragma unroll
  for (int m=0;m<2;m++)
#pragma unroll
    for (int j=0;j<4;j++){
      float inv = 1.f / lrow[m][j];
      int q = qv[m][j];
#pragma unroll
      for (int f=0;f<4;f++)
        Ob[(size_t)q*NHD + h*HD + f*16 + r] = f2bf(acc[m][f][j]*inv);
    }
}

// ---------------- launch ----------------
extern "C" void kernel_launch(void* const* d_in, const int* in_sizes, int n_in,
                              void* d_out, int out_size, void* d_ws, size_t ws_size,
                              hipStream_t stream){
  const float* hs   = (const float*)d_in[0];
  const float* cosT = (const float*)d_in[1];
  const float* sinT = (const float*)d_in[2];
  const float* Wq   = (const float*)d_in[3];
  const float* Wk   = (const float*)d_in[4];
  const float* Wv   = (const float*)d_in[5];
  const float* Wo   = (const float*)d_in[6];
  const int*   nm   = (const int*)d_in[7];

  char* ws = (char*)d_ws;
  short* hsb  = (short*)(ws);                   // 8 MB
  short* WqT  = (short*)(ws + (8ull<<20));      // 8 MB
  short* WkT  = (short*)(ws + (16ull<<20));     // 2 MB
  short* WvT  = (short*)(ws + (18ull<<20));     // 2 MB
  short* WoT  = (short*)(ws + (20ull<<20));     // 8 MB
  short* Qb   = (short*)(ws + (28ull<<20));     // 8 MB
  short* Kb   = (short*)(ws + (36ull<<20));     // 2 MB
  short* Vb   = (short*)(ws + (38ull<<20));     // 2 MB
  short* VT   = (short*)(ws + (40ull<<20));     // 2 MB
  short* VTs  = (short*)(ws + (42ull<<20));     // 2 MB
  short* attnb= (short*)(ws + (44ull<<20));     // 8 MB
  float* out  = (float*)d_out;

  k_f32_to_bf16<<<(S_LEN*HIDDEN/4+255)/256, 256, 0, stream>>>(hs, hsb, S_LEN*HIDDEN/4);
  k_transpose<<<dim3(NHD/32, HIDDEN/32), 256, 0, stream>>>(Wq, WqT, HIDDEN, NHD);
  k_transpose<<<dim3(KVD/32, HIDDEN/32), 256, 0, stream>>>(Wk, WkT, HIDDEN, KVD);
  k_transpose<<<dim3(KVD/32, HIDDEN/32), 256, 0, stream>>>(Wv, WvT, HIDDEN, KVD);
  k_transpose<<<dim3(HIDDEN/32, NHD/32), 256, 0, stream>>>(Wo, WoT, NHD, HIDDEN);

  // QKV GEMM (in-block split-K, 512 thr) + fused RoPE/scale/bf16 epilogue
  k_gemm_qkv<<<dim3(24, 16), 512, 0, stream>>>(hsb, WqT, WkT, WvT, cosT, sinT,
                                               Qb, Kb, Vb);

  k_transpose_bb<<<dim3(KVD/32, S_LEN/32), 256, 0, stream>>>(Vb, VT, S_LEN, KVD);
  k_vt_sparse_bb<<<dim3(S_LEN/32, KVD/32), 256, 0, stream>>>(Vb, VTs, nm);

  k_attn2<<<dim3(S_LEN/128, NH), 256, 0, stream>>>(Qb, Kb, VT, VTs, nm, attnb);

  k_gemm<<<dim3(NHD/128, S_LEN/128), 512, 0, stream>>>(attnb, WoT, out, HIDDEN);
}

// Round 6
// 145.734 us; speedup vs baseline: 2.0879x; 1.0415x over previous
//
#include <hip/hip_runtime.h>
#include <hip/hip_bf16.h>
#include <stdint.h>

#define S_LEN  2048
#define HIDDEN 2048
#define NH     32
#define NKVH   8
#define HD     64
#define NHD    (NH*HD)    // 2048
#define KVD    (NKVH*HD)  // 512

typedef __attribute__((ext_vector_type(8))) short  short8;
typedef __attribute__((ext_vector_type(4))) short  short4v;
typedef __attribute__((ext_vector_type(4))) float  f32x4;
typedef __attribute__((ext_vector_type(4))) float  float4v;
typedef __attribute__((ext_vector_type(8))) __bf16 bf16x8;

__device__ __forceinline__ short f2bf(float x){
  uint32_t u = __builtin_bit_cast(uint32_t, x);
  u += 0x7fffu + ((u >> 16) & 1u);   // RNE; inputs are finite
  return (short)(u >> 16);
}

__device__ __forceinline__ f32x4 mfma_bf16(short8 a, short8 b, f32x4 c){
  return __builtin_amdgcn_mfma_f32_16x16x32_bf16(
      __builtin_bit_cast(bf16x8, a), __builtin_bit_cast(bf16x8, b), c, 0, 0, 0);
}

// async global->LDS, 16B per lane; LDS dest = wave-uniform base + lane*16
__device__ __forceinline__ void gload16(const short* g, short* l){
  __builtin_amdgcn_global_load_lds(
      (const __attribute__((address_space(1))) void*)g,
      (__attribute__((address_space(3))) void*)l, 16, 0, 0);
}

// ---------------- elementwise fp32 -> bf16 ----------------
__global__ __launch_bounds__(256) void k_f32_to_bf16(const float* __restrict__ X,
                                                     short* __restrict__ Y, int n4){
  int i = blockIdx.x*256 + threadIdx.x;
  if (i >= n4) return;
  float4v v = ((const float4v* __restrict__)X)[i];
  short4v o;
#pragma unroll
  for (int j=0;j<4;j++) o[j] = f2bf(v[j]);
  ((short4v* __restrict__)Y)[i] = o;
}

// ---------------- transpose fp32 (R x C) -> bf16 (C x R) ----------------
__global__ __launch_bounds__(256) void k_transpose(const float* __restrict__ W,
                                                   short* __restrict__ WT, int R, int C){
  __shared__ float tile[32][33];
  int x = threadIdx.x & 31, y0 = threadIdx.x >> 5;
  int c0 = blockIdx.x*32, r0 = blockIdx.y*32;
#pragma unroll
  for (int yy=y0; yy<32; yy+=8) tile[yy][x] = W[(size_t)(r0+yy)*C + c0 + x];
  __syncthreads();
#pragma unroll
  for (int yy=y0; yy<32; yy+=8) WT[(size_t)(c0+yy)*R + r0 + x] = f2bf(tile[x][yy]);
}

// ---------------- transpose bf16 (R x C) -> bf16 (C x R) ----------------
__global__ __launch_bounds__(256) void k_transpose_bb(const short* __restrict__ V,
                                                      short* __restrict__ VT, int R, int C){
  __shared__ short tile[32][33];
  int x = threadIdx.x & 31, y0 = threadIdx.x >> 5;
  int c0 = blockIdx.x*32, r0 = blockIdx.y*32;
#pragma unroll
  for (int yy=y0; yy<32; yy+=8) tile[yy][x] = V[(size_t)(r0+yy)*C + c0 + x];
  __syncthreads();
#pragma unroll
  for (int yy=y0; yy<32; yy+=8) VT[(size_t)(c0+yy)*R + r0 + x] = tile[x][yy];
}

// ---- sparse-column V transpose (bf16 in): VTs[d][c] = V[bs*c][d] ----
__global__ __launch_bounds__(256) void k_vt_sparse_bb(const short* __restrict__ V,
                                                      short* __restrict__ VTs,
                                                      const int* __restrict__ nm){
  int bs = nm[0] + 1;
  int Sc = S_LEN / bs;
  __shared__ short tile[32][33];
  int x = threadIdx.x & 31, y0 = threadIdx.x >> 5;
  int c0 = blockIdx.x*32, d0 = blockIdx.y*32;
  if (c0 >= Sc) return;
#pragma unroll
  for (int yy=y0; yy<32; yy+=8) tile[yy][x] = V[(size_t)(bs*(c0+yy))*KVD + d0 + x];
  __syncthreads();
#pragma unroll
  for (int yy=y0; yy<32; yy+=8) VTs[(size_t)(d0+yy)*S_LEN + c0 + x] = tile[x][yy];
}

// ==== 512-thread in-block split-K GEMM core =====================================
struct GemmIdx {
  int wid, r, g, wr, wc, kg, gtid;
};
__device__ __forceinline__ GemmIdx gemm_idx(){
  GemmIdx ix;
  int tid = threadIdx.x, lane = tid&63;
  ix.kg = tid>>8; ix.gtid = tid&255;
  ix.wid = (tid>>6)&3; ix.r = lane&15; ix.g = lane>>4;
  ix.wr = ix.wid>>1; ix.wc = ix.wid&1;
  return ix;
}

__device__ __forceinline__ void stage128(const short* gA, const short* gB,
                                         short* As, short* Bs, int kt, int w){
  const int K = HIDDEN;
  gload16(gA + kt*32,                As + w*512);
  gload16(gA + (size_t)64*K + kt*32, As + 2048 + w*512);
  gload16(gB + kt*32,                Bs + w*512);
  gload16(gB + (size_t)64*K + kt*32, Bs + 2048 + w*512);
}

__device__ __forceinline__ void compute128(const short* As, const short* Bs,
                                           f32x4 acc[4][4], const GemmIdx& ix){
  short8 af[4], bf[4];
#pragma unroll
  for (int m=0;m<4;m++) af[m] = *(const short8*)&As[(ix.wr*64 + m*16 + ix.r)*32 + ix.g*8];
#pragma unroll
  for (int n=0;n<4;n++) bf[n] = *(const short8*)&Bs[(ix.wc*64 + n*16 + ix.r)*32 + ix.g*8];
#pragma unroll
  for (int m=0;m<4;m++)
#pragma unroll
    for (int n=0;n<4;n++) acc[m][n] = mfma_bf16(af[m], bf[n], acc[m][n]);
}

__device__ __forceinline__ void gemm_core512(const short* __restrict__ A,
                                             const short* __restrict__ BT,
                                             int bm, int bn, short* LDS,
                                             f32x4 acc[4][4], const GemmIdx& ix){
  const int K = HIDDEN;
  const short* gA = A  + (size_t)(bm*128 + (ix.gtid>>2))*K + ix.kg*1024 + (ix.gtid&3)*8;
  const short* gB = BT + (size_t)(bn*128 + (ix.gtid>>2))*K + ix.kg*1024 + (ix.gtid&3)*8;
  short* L   = LDS + ix.kg*16384;
  short* As0 = L;        short* Bs0 = L + 4096;
  short* As1 = L + 8192; short* Bs1 = L + 12288;
  const int w = ix.gtid>>6;

#pragma unroll
  for (int m=0;m<4;m++)
#pragma unroll
    for (int n=0;n<4;n++) acc[m][n] = (f32x4){0.f,0.f,0.f,0.f};

  const int nkt = 32;                   // K=1024 per group, BK=32
  stage128(gA, gB, As0, Bs0, 0, w);
  __syncthreads();                      // buf0 ready (vmcnt(0)+barrier)
  for (int u=0; u<nkt/2; ++u){
    const int t = 2*u;
    if (t+1 < nkt) stage128(gA, gB, As1, Bs1, t+1, w);   // in flight under compute
    compute128(As0, Bs0, acc, ix);
    __syncthreads();                    // buf1 landed; buf0 free
    if (t+2 < nkt) stage128(gA, gB, As0, Bs0, t+2, w);
    compute128(As1, Bs1, acc, ix);
    __syncthreads();
  }

  // cross-group reduce: group1 -> LDS, group0 adds
  float* red = (float*)LDS;
  if (ix.kg){
#pragma unroll
    for (int m=0;m<4;m++)
#pragma unroll
      for (int n=0;n<4;n++)
#pragma unroll
        for (int j=0;j<4;j++)
          red[ix.wid*4096 + (m*16 + ix.g*4 + j)*64 + n*16 + ix.r] = acc[m][n][j];
  }
  __syncthreads();
  if (!ix.kg){
#pragma unroll
    for (int m=0;m<4;m++)
#pragma unroll
      for (int n=0;n<4;n++)
#pragma unroll
        for (int j=0;j<4;j++)
          acc[m][n][j] += red[ix.wid*4096 + (m*16 + ix.g*4 + j)*64 + n*16 + ix.r];
  }
}

// QKV GEMM with fused RoPE + scale + bf16 epilogue (group 0 only).
__global__ __launch_bounds__(512, 4) void k_gemm_qkv(const short* __restrict__ hsb,
                                                     const short* __restrict__ WqT,
                                                     const short* __restrict__ WkT,
                                                     const short* __restrict__ WvT,
                                                     const float* __restrict__ cosT,
                                                     const float* __restrict__ sinT,
                                                     short* __restrict__ Qb,
                                                     short* __restrict__ Kb,
                                                     short* __restrict__ Vb){
  __shared__ short LDS[32768];
  const int bn = blockIdx.x, bm = blockIdx.y;
  GemmIdx ix = gemm_idx();
  f32x4 acc[4][4];

  if (bn < 16){
    gemm_core512(hsb, WqT + (size_t)bn*128*HIDDEN, bm, 0, LDS, acc, ix);
    if (ix.kg) return;
    const int h2 = bn*2 + ix.wc;
#pragma unroll
    for (int m=0;m<4;m++)
#pragma unroll
      for (int j=0;j<4;j++){
        const int s = bm*128 + ix.wr*64 + m*16 + ix.g*4 + j;
        const float* cr = cosT + s*64;
        const float* sr = sinT + s*64;
#pragma unroll
        for (int n=0;n<2;n++){
          const int d = n*16 + ix.r;
          float x1 = acc[m][n][j], x2 = acc[m][n+2][j];
          Qb[(size_t)s*NHD + h2*64 + d]      = f2bf((x1*cr[d]    - x2*sr[d])   *0.125f);
          Qb[(size_t)s*NHD + h2*64 + d + 32] = f2bf((x2*cr[d+32] + x1*sr[d+32])*0.125f);
        }
      }
  } else if (bn < 20){
    gemm_core512(hsb, WkT + (size_t)(bn-16)*128*HIDDEN, bm, 0, LDS, acc, ix);
    if (ix.kg) return;
    const int h2 = (bn-16)*2 + ix.wc;
#pragma unroll
    for (int m=0;m<4;m++)
#pragma unroll
      for (int j=0;j<4;j++){
        const int s = bm*128 + ix.wr*64 + m*16 + ix.g*4 + j;
        const float* cr = cosT + s*64;
        const float* sr = sinT + s*64;
#pragma unroll
        for (int n=0;n<2;n++){
          const int d = n*16 + ix.r;
          float x1 = acc[m][n][j], x2 = acc[m][n+2][j];
          Kb[(size_t)s*KVD + h2*64 + d]      = f2bf(x1*cr[d]    - x2*sr[d]);
          Kb[(size_t)s*KVD + h2*64 + d + 32] = f2bf(x2*cr[d+32] + x1*sr[d+32]);
        }
      }
  } else {
    gemm_core512(hsb, WvT + (size_t)(bn-20)*128*HIDDEN, bm, 0, LDS, acc, ix);
    if (ix.kg) return;
    const int c0 = (bn-20)*128 + ix.wc*64;
#pragma unroll
    for (int m=0;m<4;m++)
#pragma unroll
      for (int n=0;n<4;n++)
#pragma unroll
        for (int j=0;j<4;j++){
          const int s = bm*128 + ix.wr*64 + m*16 + ix.g*4 + j;
          Vb[(size_t)s*KVD + c0 + n*16 + ix.r] = f2bf(acc[m][n][j]);
        }
  }
}

// generic in-block split-K GEMM, fp32 output
__global__ __launch_bounds__(512, 4) void k_gemm(const short* __restrict__ A,
                                                 const short* __restrict__ BT,
                                                 float* __restrict__ C, int Nc){
  __shared__ short LDS[32768];
  const int bn = blockIdx.x, bm = blockIdx.y;
  GemmIdx ix = gemm_idx();
  f32x4 acc[4][4];
  gemm_core512(A, BT, bm, bn, LDS, acc, ix);
  if (ix.kg) return;
#pragma unroll
  for (int m=0;m<4;m++)
#pragma unroll
    for (int n=0;n<4;n++)
#pragma unroll
      for (int j=0;j<4;j++)
        C[(size_t)(bm*128 + ix.wr*64 + m*16 + ix.g*4 + j)*Nc
          + bn*128 + ix.wc*64 + n*16 + ix.r] = acc[m][n][j];
}

// ======================= attention v3: 1-wave blocks ===========================
// 16 q-rows per 64-thread block; grid (S/16)*NH heavy-first; no barriers.
// Column pass: dense over keys k=bs*c (pre-gathered V^T); diag: 16-key fragment.

// softmax + PV tail for one full 64-key tile (single m-frag)
__device__ __forceinline__ void sm_pv1(f32x4 sc[4],
                                       float mrow[4], float lrow[4],
                                       f32x4 acc[4], short* Pw,
                                       const short* Vtile,   // [d][col], stride S_LEN
                                       int r, int g){
#pragma unroll
  for (int j=0;j<4;j++){
    float v = fmaxf(fmaxf(sc[0][j], sc[1][j]), fmaxf(sc[2][j], sc[3][j]));
    v = fmaxf(v, __shfl_xor(v, 1));
    v = fmaxf(v, __shfl_xor(v, 2));
    v = fmaxf(v, __shfl_xor(v, 4));
    v = fmaxf(v, __shfl_xor(v, 8));
    float mn = fmaxf(mrow[j], v);
    float fac = __expf(mrow[j] - mn);
    mrow[j] = mn;
#pragma unroll
    for (int f=0;f<4;f++) acc[f][j] *= fac;
    float rs = 0.f;
#pragma unroll
    for (int n=0;n<4;n++){
      float p = __expf(sc[n][j] - mn);
      rs += p;
      sc[n][j] = p;
    }
    rs += __shfl_xor(rs, 1);
    rs += __shfl_xor(rs, 2);
    rs += __shfl_xor(rs, 4);
    rs += __shfl_xor(rs, 8);
    lrow[j] = lrow[j]*fac + rs;
  }
  // P -> LDS (C-layout write, A-layout read; same wave -> lgkm ordering only)
#pragma unroll
  for (int n=0;n<4;n++)
#pragma unroll
    for (int j=0;j<4;j++)
      Pw[(g*4+j)*72 + n*16 + r] = f2bf(sc[n][j]);

  short8 pf0 = *(short8*)&Pw[r*72 + g*8];
  short8 pf1 = *(short8*)&Pw[r*72 + 32 + g*8];
#pragma unroll
  for (int f=0;f<4;f++){
    short8 vf0 = *(const short8*)(Vtile + (size_t)(f*16 + r)*S_LEN + g*8);
    short8 vf1 = *(const short8*)(Vtile + (size_t)(f*16 + r)*S_LEN + 32 + g*8);
    acc[f] = mfma_bf16(pf0, vf0, acc[f]);
    acc[f] = mfma_bf16(pf1, vf1, acc[f]);
  }
}

__global__ __launch_bounds__(64, 4) void k_attn3(const short* __restrict__ Qb,
                                                 const short* __restrict__ Kb,   // [S][KVD]
                                                 const short* __restrict__ VT,   // [KVD][S]
                                                 const short* __restrict__ VTs,  // [KVD][S/bs], stride S
                                                 const int* __restrict__ nm,
                                                 short* __restrict__ Ob){
  const int i  = gridDim.x - 1 - blockIdx.x;   // heavy q-sub-blocks first
  const int qs = i >> 5;                       // 16-row sub-block index, 0..127
  const int h  = i & 31;
  const int hk = h >> 2;
  const int bs = nm[0] + 1;                    // requires bs | 16

  const int lane = threadIdx.x;
  const int r = lane&15, g = lane>>4;

  __shared__ short Pw[16*72];

  const int qlo = qs*16;

  // Q fragments (scale pre-folded): lane r holds row qlo+r
  short8 qf0 = *(const short8*)(Qb + (size_t)(qlo + r)*NHD + h*HD + g*8);
  short8 qf1 = *(const short8*)(Qb + (size_t)(qlo + r)*NHD + h*HD + 32 + g*8);

  f32x4 acc[4];
  float mrow[4], lrow[4];
#pragma unroll
  for (int f=0;f<4;f++) acc[f] = (f32x4){0.f,0.f,0.f,0.f};
#pragma unroll
  for (int j=0;j<4;j++){ mrow[j] = -1e30f; lrow[j] = 0.f; }

  const short* Kg  = Kb  + hk*HD;
  const short* Vsg = VTs + (size_t)hk*HD*S_LEN;
  const short* Vdg = VT  + (size_t)hk*HD*S_LEN;

  // ---- column pass: keys k = bs*c for c < cmax (all causally allowed) ----
  const int cmax = qlo / bs;                   // exact (bs | 16)
  const int nct = (cmax + 63) >> 6;
  for (int ct=0; ct<nct; ++ct){
    const int cbase = ct*64;
    f32x4 sc[4];
#pragma unroll
    for (int n=0;n<4;n++){
      const int key = bs*(cbase + n*16 + r);
      short8 kf0 = *(const short8*)(Kg + (size_t)key*KVD + g*8);
      short8 kf1 = *(const short8*)(Kg + (size_t)key*KVD + 32 + g*8);
      f32x4 z = (f32x4){0.f,0.f,0.f,0.f};
      z = mfma_bf16(qf0, kf0, z);
      sc[n] = mfma_bf16(qf1, kf1, z);
    }
    if (cmax - cbase < 64){                    // partial last tile only
#pragma unroll
      for (int n=0;n<4;n++){
        if (cbase + n*16 + r >= cmax){
#pragma unroll
          for (int j=0;j<4;j++) sc[n][j] = -1e30f;
        }
      }
    }
    sm_pv1(sc, mrow, lrow, acc, Pw, Vsg + cbase, r, g);
  }

  // ---- diag: the 16 keys [qlo, qlo+16) with the full mask ----
  {
    const int key = qlo + r;                   // one 16-key fragment (n=0)
    short8 kf0 = *(const short8*)(Kg + (size_t)key*KVD + g*8);
    short8 kf1 = *(const short8*)(Kg + (size_t)key*KVD + 32 + g*8);
    f32x4 z = (f32x4){0.f,0.f,0.f,0.f};
    z = mfma_bf16(qf0, kf0, z);
    f32x4 sc0 = mfma_bf16(qf1, kf1, z);

    const int rb = r / bs, rm = r % bs;        // few runtime divs, once
#pragma unroll
    for (int j=0;j<4;j++){
      const int qrel = g*4 + j;
      bool ok = (r <= qrel) && ((rm == 0) || (rb == qrel/bs));
      sc0[j] = ok ? sc0[j] : -1e30f;
    }

    // softmax round over the single fragment
#pragma unroll
    for (int j=0;j<4;j++){
      float v = sc0[j];
      v = fmaxf(v, __shfl_xor(v, 1));
      v = fmaxf(v, __shfl_xor(v, 2));
      v = fmaxf(v, __shfl_xor(v, 4));
      v = fmaxf(v, __shfl_xor(v, 8));
      float mn = fmaxf(mrow[j], v);
      float fac = __expf(mrow[j] - mn);
      mrow[j] = mn;
#pragma unroll
      for (int f=0;f<4;f++) acc[f][j] *= fac;
      float p = __expf(sc0[j] - mn);
      sc0[j] = p;
      float rs = p;
      rs += __shfl_xor(rs, 1);
      rs += __shfl_xor(rs, 2);
      rs += __shfl_xor(rs, 4);
      rs += __shfl_xor(rs, 8);
      lrow[j] = lrow[j]*fac + rs;
    }
    // P cols 0..15 = probs, cols 16..31 = 0 (keys beyond the 16-key band)
#pragma unroll
    for (int j=0;j<4;j++){
      Pw[(g*4+j)*72 + r]      = f2bf(sc0[j]);
      Pw[(g*4+j)*72 + 16 + r] = 0;
    }
    short8 pf0 = *(short8*)&Pw[r*72 + g*8];    // covers cols 0..31 (16..31 zero)
#pragma unroll
    for (int f=0;f<4;f++){
      short8 vf0 = *(const short8*)(Vdg + (size_t)(f*16 + r)*S_LEN + qlo + g*8);
      acc[f] = mfma_bf16(pf0, vf0, acc[f]);
    }
  }

  // epilogue: O /= l, write bf16 (rows qlo + g*4 + j)
#pragma unroll
  for (int j=0;j<4;j++){
    float inv = 1.f / lrow[j];
    const int q = qlo + g*4 + j;
#pragma unroll
    for (int f=0;f<4;f++)
      Ob[(size_t)q*NHD + h*HD + f*16 + r] = f2bf(acc[f][j]*inv);
  }
}

// ---------------- launch ----------------
extern "C" void kernel_launch(void* const* d_in, const int* in_sizes, int n_in,
                              void* d_out, int out_size, void* d_ws, size_t ws_size,
                              hipStream_t stream){
  const float* hs   = (const float*)d_in[0];
  const float* cosT = (const float*)d_in[1];
  const float* sinT = (const float*)d_in[2];
  const float* Wq   = (const float*)d_in[3];
  const float* Wk   = (const float*)d_in[4];
  const float* Wv   = (const float*)d_in[5];
  const float* Wo   = (const float*)d_in[6];
  const int*   nm   = (const int*)d_in[7];

  char* ws = (char*)d_ws;
  short* hsb  = (short*)(ws);                   // 8 MB
  short* WqT  = (short*)(ws + (8ull<<20));      // 8 MB
  short* WkT  = (short*)(ws + (16ull<<20));     // 2 MB
  short* WvT  = (short*)(ws + (18ull<<20));     // 2 MB
  short* WoT  = (short*)(ws + (20ull<<20));     // 8 MB
  short* Qb   = (short*)(ws + (28ull<<20));     // 8 MB
  short* Kb   = (short*)(ws + (36ull<<20));     // 2 MB
  short* Vb   = (short*)(ws + (38ull<<20));     // 2 MB
  short* VT   = (short*)(ws + (40ull<<20));     // 2 MB
  short* VTs  = (short*)(ws + (42ull<<20));     // 2 MB
  short* attnb= (short*)(ws + (44ull<<20));     // 8 MB
  float* out  = (float*)d_out;

  k_f32_to_bf16<<<(S_LEN*HIDDEN/4+255)/256, 256, 0, stream>>>(hs, hsb, S_LEN*HIDDEN/4);
  k_transpose<<<dim3(NHD/32, HIDDEN/32), 256, 0, stream>>>(Wq, WqT, HIDDEN, NHD);
  k_transpose<<<dim3(KVD/32, HIDDEN/32), 256, 0, stream>>>(Wk, WkT, HIDDEN, KVD);
  k_transpose<<<dim3(KVD/32, HIDDEN/32), 256, 0, stream>>>(Wv, WvT, HIDDEN, KVD);
  k_transpose<<<dim3(HIDDEN/32, NHD/32), 256, 0, stream>>>(Wo, WoT, NHD, HIDDEN);

  // QKV GEMM (in-block split-K, 512 thr) + fused RoPE/scale/bf16 epilogue
  k_gemm_qkv<<<dim3(24, 16), 512, 0, stream>>>(hsb, WqT, WkT, WvT, cosT, sinT,
                                               Qb, Kb, Vb);

  k_transpose_bb<<<dim3(KVD/32, S_LEN/32), 256, 0, stream>>>(Vb, VT, S_LEN, KVD);
  k_vt_sparse_bb<<<dim3(S_LEN/32, KVD/32), 256, 0, stream>>>(Vb, VTs, nm);

  k_attn3<<<dim3((S_LEN/16)*NH), 64, 0, stream>>>(Qb, Kb, VT, VTs, nm, attnb);

  k_gemm<<<dim3(NHD/128, S_LEN/128), 512, 0, stream>>>(attnb, WoT, out, HIDDEN);
}